// Round 7
// baseline (777.947 us; speedup 1.0000x reference)
//
#include <hip/hip_runtime.h>

#define N_NODES 100000
#define N_EDGES 600000
#define IN_CH 5
#define HID 128

// ---------------- edge dtype detection (int64 vs int32 layout) ----------------
__global__ __launch_bounds__(256) void k_detect(const unsigned* __restrict__ E, int* __restrict__ flag) {
    int t = blockIdx.x * blockDim.x + threadIdx.x;
    if (t < 4096) {
        if (E[2 * t + 1] != 0u) atomicOr(flag, 1);
    }
}

__device__ __forceinline__ int edge_elem(const unsigned* __restrict__ E, int elem, int is64) {
    return (int)E[is64 ? (2 * elem) : elem];
}

// ---------------- degree count ----------------
__global__ __launch_bounds__(256) void k_count(const unsigned* __restrict__ E, const int* __restrict__ flag,
                                               int* __restrict__ deg) {
    int e = blockIdx.x * blockDim.x + threadIdx.x;
    int is64 = (*flag == 0) ? 1 : 0;
    if (e < N_EDGES) {
        int d = edge_elem(E, N_EDGES + e, is64);
        atomicAdd(&deg[d], 1);
    }
}

// ---------------- exclusive scan (3-kernel), dinv fused into pass 1 ----------------
__global__ __launch_bounds__(256) void k_scan1(const int* __restrict__ deg, int* __restrict__ offs,
                                               int* __restrict__ bsum, float* __restrict__ dinv) {
    __shared__ int sd[256];
    int t = threadIdx.x;
    int base = blockIdx.x * 1024 + t * 4;
    int v0 = (base + 0 < N_NODES) ? deg[base + 0] : 0;
    int v1 = (base + 1 < N_NODES) ? deg[base + 1] : 0;
    int v2 = (base + 2 < N_NODES) ? deg[base + 2] : 0;
    int v3 = (base + 3 < N_NODES) ? deg[base + 3] : 0;
    if (base + 0 < N_NODES) dinv[base + 0] = rsqrtf((float)v0 + 1.0f);
    if (base + 1 < N_NODES) dinv[base + 1] = rsqrtf((float)v1 + 1.0f);
    if (base + 2 < N_NODES) dinv[base + 2] = rsqrtf((float)v2 + 1.0f);
    if (base + 3 < N_NODES) dinv[base + 3] = rsqrtf((float)v3 + 1.0f);
    sd[t] = v0 + v1 + v2 + v3;
    __syncthreads();
    for (int off = 1; off < 256; off <<= 1) {
        int x = sd[t];
        if (t >= off) x += sd[t - off];
        __syncthreads();
        sd[t] = x;
        __syncthreads();
    }
    int run = (t == 0) ? 0 : sd[t - 1];
    if (base + 0 < N_NODES) offs[base + 0] = run; run += v0;
    if (base + 1 < N_NODES) offs[base + 1] = run; run += v1;
    if (base + 2 < N_NODES) offs[base + 2] = run; run += v2;
    if (base + 3 < N_NODES) offs[base + 3] = run;
    if (t == 255) bsum[blockIdx.x] = sd[255];
}

__global__ __launch_bounds__(256) void k_scan2(int* __restrict__ bsum, int nb) {
    __shared__ int sd[256];
    int t = threadIdx.x;
    sd[t] = (t < nb) ? bsum[t] : 0;
    __syncthreads();
    for (int off = 1; off < 256; off <<= 1) {
        int x = sd[t];
        if (t >= off) x += sd[t - off];
        __syncthreads();
        sd[t] = x;
        __syncthreads();
    }
    if (t < nb) bsum[t] = (t == 0) ? 0 : sd[t - 1];
}

__global__ __launch_bounds__(256) void k_scan3(int* __restrict__ offs, const int* __restrict__ bsum) {
    int i = blockIdx.x * blockDim.x + threadIdx.x;
    if (i < N_NODES) offs[i] += bsum[i >> 10];
    if (i == 0) offs[N_NODES] = N_EDGES;
}

// ---------------- CSR fill ----------------
__global__ __launch_bounds__(256) void k_fill(const unsigned* __restrict__ E, const int* __restrict__ flag,
                                              const float* __restrict__ dinv, const int* __restrict__ offs,
                                              int* __restrict__ cursor, int* __restrict__ csr_src,
                                              float* __restrict__ csr_w) {
    int e = blockIdx.x * blockDim.x + threadIdx.x;
    int is64 = (*flag == 0) ? 1 : 0;
    if (e < N_EDGES) {
        int s = edge_elem(E, e, is64);
        int d = edge_elem(E, N_EDGES + e, is64);
        int p = atomicAdd(&cursor[d], 1);
        int idx = offs[d] + p;
        csr_src[idx] = s;
        csr_w[idx] = dinv[s] * dinv[d];
    }
}

// ---------------- layer 0: aggregate on 6-wide input ----------------
__global__ __launch_bounds__(256) void k_agg6(const float* __restrict__ x, const float* __restrict__ sdf,
                                              const float* __restrict__ dinv, const int* __restrict__ offs,
                                              const int* __restrict__ csr_src, const float* __restrict__ csr_w,
                                              float* __restrict__ g) {
    int i = blockIdx.x * blockDim.x + threadIdx.x;
    if (i >= N_NODES) return;
    float dn = dinv[i];
    float dn2 = dn * dn;
    float a[6];
#pragma unroll
    for (int f = 0; f < IN_CH; f++) a[f] = dn2 * x[i * IN_CH + f];
    a[5] = dn2 * sdf[i];
    int e0 = offs[i], e1 = offs[i + 1];
    for (int e = e0; e < e1; e++) {
        int s = csr_src[e];
        float w = csr_w[e];
#pragma unroll
        for (int f = 0; f < IN_CH; f++) a[f] += w * x[s * IN_CH + f];
        a[5] += w * sdf[s];
    }
#pragma unroll
    for (int f = 0; f < 6; f++) g[i * 6 + f] = a[f];
}

// ---------------- layer 0 GEMM: [N,6] @ [6,128] + b, relu ----------------
__global__ __launch_bounds__(256) void k_gemm6(const float* __restrict__ g, const float* __restrict__ W,
                                               const float* __restrict__ b, float* __restrict__ out) {
    __shared__ float Ws[6 * 128];
    __shared__ float bs[128];
    int t = threadIdx.x;
    for (int j = t; j < 768; j += 256) Ws[j] = W[j];
    if (t < 128) bs[t] = b[t];
    __syncthreads();
    int node = blockIdx.x * 2 + (t >> 7);
    int f = t & 127;
    if (node >= N_NODES) return;
    float acc = bs[f];
#pragma unroll
    for (int k = 0; k < 6; k++) acc += g[node * 6 + k] * Ws[k * 128 + f];
    out[node * 128 + f] = fmaxf(acc, 0.0f);
}

// ---------------- fused hidden layer: out = relu((A_hat h) W + b) ----------------
// Block = 64 nodes. Phase 1: 16-lane groups aggregate rows into LDS At[k][row]
// (transposed, stride 68; lane owns k = sub+16m -> writes are 2-way max = free).
// Phase 2: 64x128 @ 128x128 GEMM from LDS (R6 inner loop), W reg-prefetch
// issued BEFORE phase 1 so its fetch hides under the gather. 51 KB LDS.
__global__ __launch_bounds__(256) void k_fused(const float* __restrict__ h, const float* __restrict__ W,
                                               const float* __restrict__ bias, const float* __restrict__ dinv,
                                               const int* __restrict__ offs, const int* __restrict__ csr_src,
                                               const float* __restrict__ csr_w, float* __restrict__ out) {
    __shared__ float At[128 * 68];  // [k][row] transposed
    __shared__ float Bs[32 * 128];  // [k][col] per-kb
    int t = threadIdx.x;
    int row0 = blockIdx.x * 64;

    // B staging coords + kb=0 prefetch (in flight during phase 1)
    int kbi[4], cb[4];
#pragma unroll
    for (int j = 0; j < 4; j++) {
        int lin = t + j * 256;
        kbi[j] = lin >> 5;
        cb[j] = (lin & 31) * 4;
    }
    float4 pb[4];
#pragma unroll
    for (int j = 0; j < 4; j++) pb[j] = *(const float4*)&W[(size_t)kbi[j] * 128 + cb[j]];

    // ---- phase 1: aggregate 64 rows into At ----
    int grp = t >> 4;  // 0..15: node group
    int sub = t & 15;  // feature lane: k = sub + 16*m
    for (int rr = 0; rr < 4; ++rr) {
        int r = grp + 16 * rr;
        int node = row0 + r;
        float a[8];
        if (node < N_NODES) {
            float dn = dinv[node];
            float dn2 = dn * dn;
            const float* hp = &h[(size_t)node * 128 + sub];
#pragma unroll
            for (int m = 0; m < 8; m++) a[m] = dn2 * hp[16 * m];
            int e0 = offs[node], e1 = offs[node + 1];
            if (e0 < e1) {
                int s = csr_src[e0];
                float w = csr_w[e0];
                for (int e = e0; e + 1 < e1; ++e) {
                    int s2 = csr_src[e + 1];
                    float w2 = csr_w[e + 1];
                    const float* up = &h[(size_t)s * 128 + sub];
#pragma unroll
                    for (int m = 0; m < 8; m++) a[m] += w * up[16 * m];
                    s = s2;
                    w = w2;
                }
                const float* up = &h[(size_t)s * 128 + sub];
#pragma unroll
                for (int m = 0; m < 8; m++) a[m] += w * up[16 * m];
            }
        } else {
#pragma unroll
            for (int m = 0; m < 8; m++) a[m] = 0.0f;
        }
#pragma unroll
        for (int m = 0; m < 8; m++) At[(sub + 16 * m) * 68 + r] = a[m];
    }
    __syncthreads();

    // ---- phase 2: GEMM from LDS ----
    int tr = t >> 5;   // 0..7 -> rows tr*8..tr*8+7
    int tc = t & 31;   // cols tc*4..tc*4+3
    float acc[8][4];
#pragma unroll
    for (int r = 0; r < 8; r++)
#pragma unroll
        for (int c = 0; c < 4; c++) acc[r][c] = 0.0f;

    for (int kb = 0; kb < 4; kb++) {
        if (kb > 0) __syncthreads();  // prior compute done reading Bs
#pragma unroll
        for (int j = 0; j < 4; j++) *(float4*)&Bs[kbi[j] * 128 + cb[j]] = pb[j];
        __syncthreads();
        if (kb < 3) {
#pragma unroll
            for (int j = 0; j < 4; j++)
                pb[j] = *(const float4*)&W[(size_t)((kb + 1) * 32 + kbi[j]) * 128 + cb[j]];
        }
#pragma unroll
        for (int k = 0; k < 32; k++) {
            int kk = kb * 32 + k;
            float4 a0 = *(const float4*)&At[kk * 68 + tr * 8];
            float4 a1 = *(const float4*)&At[kk * 68 + tr * 8 + 4];
            float4 bv = *(const float4*)&Bs[k * 128 + tc * 4];
            float ar[8] = {a0.x, a0.y, a0.z, a0.w, a1.x, a1.y, a1.z, a1.w};
            float bc[4] = {bv.x, bv.y, bv.z, bv.w};
#pragma unroll
            for (int r = 0; r < 8; r++)
#pragma unroll
                for (int c = 0; c < 4; c++) acc[r][c] += ar[r] * bc[c];
        }
    }

    // ---- epilogue: bias + relu ----
    float4 bv = *(const float4*)&bias[tc * 4];
#pragma unroll
    for (int r = 0; r < 8; r++) {
        int grow = row0 + tr * 8 + r;
        if (grow < N_NODES) {
            float4 o;
            o.x = fmaxf(acc[r][0] + bv.x, 0.0f);
            o.y = fmaxf(acc[r][1] + bv.y, 0.0f);
            o.z = fmaxf(acc[r][2] + bv.z, 0.0f);
            o.w = fmaxf(acc[r][3] + bv.w, 0.0f);
            *(float4*)&out[(size_t)grow * 128 + tc * 4] = o;
        }
    }
}

// ---------------- final GEMM: [N,128] @ [128,3] ----------------
__global__ __launch_bounds__(256) void k_gemm3(const float* __restrict__ H, const float* __restrict__ W,
                                               float* __restrict__ out) {
    __shared__ float Ws[128 * 3];
    int t = threadIdx.x;
    for (int j = t; j < 384; j += 256) Ws[j] = W[j];
    __syncthreads();
    int i = blockIdx.x * 256 + t;
    if (i >= N_NODES) return;
    float a0 = 0.f, a1 = 0.f, a2 = 0.f;
#pragma unroll
    for (int k = 0; k < 128; k += 4) {
        float4 v = *(const float4*)&H[(size_t)i * 128 + k];
        a0 += v.x * Ws[(k + 0) * 3 + 0] + v.y * Ws[(k + 1) * 3 + 0] + v.z * Ws[(k + 2) * 3 + 0] + v.w * Ws[(k + 3) * 3 + 0];
        a1 += v.x * Ws[(k + 0) * 3 + 1] + v.y * Ws[(k + 1) * 3 + 1] + v.z * Ws[(k + 2) * 3 + 1] + v.w * Ws[(k + 3) * 3 + 1];
        a2 += v.x * Ws[(k + 0) * 3 + 2] + v.y * Ws[(k + 1) * 3 + 2] + v.z * Ws[(k + 2) * 3 + 2] + v.w * Ws[(k + 3) * 3 + 2];
    }
    out[(size_t)i * 3 + 0] = a0;
    out[(size_t)i * 3 + 1] = a1;
    out[(size_t)i * 3 + 2] = a2;
}

// ---------------- final aggregation on 3 feats + bias (no relu) ----------------
__global__ __launch_bounds__(256) void k_agg3(const float* __restrict__ xw3, const float* __restrict__ b,
                                              const float* __restrict__ dinv, const int* __restrict__ offs,
                                              const int* __restrict__ csr_src, const float* __restrict__ csr_w,
                                              float* __restrict__ out) {
    int i = blockIdx.x * blockDim.x + threadIdx.x;
    if (i >= N_NODES) return;
    float dn = dinv[i];
    float dn2 = dn * dn;
    float a0 = dn2 * xw3[(size_t)i * 3 + 0];
    float a1 = dn2 * xw3[(size_t)i * 3 + 1];
    float a2 = dn2 * xw3[(size_t)i * 3 + 2];
    int e0 = offs[i], e1 = offs[i + 1];
    for (int e = e0; e < e1; e++) {
        int s = csr_src[e];
        float w = csr_w[e];
        a0 += w * xw3[(size_t)s * 3 + 0];
        a1 += w * xw3[(size_t)s * 3 + 1];
        a2 += w * xw3[(size_t)s * 3 + 2];
    }
    out[(size_t)i * 3 + 0] = a0 + b[0];
    out[(size_t)i * 3 + 1] = a1 + b[1];
    out[(size_t)i * 3 + 2] = a2 + b[2];
}

extern "C" void kernel_launch(void* const* d_in, const int* in_sizes, int n_in,
                              void* d_out, int out_size, void* d_ws, size_t ws_size,
                              hipStream_t stream) {
    const float* x = (const float*)d_in[0];
    const float* sdf = (const float*)d_in[1];
    const unsigned* E = (const unsigned*)d_in[2];
    const float* Wl[6];
    const float* bl[6];
    for (int l = 0; l < 6; l++) {
        Wl[l] = (const float*)d_in[3 + 2 * l];
        bl[l] = (const float*)d_in[4 + 2 * l];
    }

    char* ws = (char*)d_ws;
    size_t off = 0;
    auto alloc = [&](size_t bytes) -> void* {
        void* p = ws + off;
        off += (bytes + 255) / 256 * 256;
        return p;
    };
    int* flag = (int*)alloc(4);
    int* deg = (int*)alloc((size_t)N_NODES * 4);
    int* cursor = (int*)alloc((size_t)N_NODES * 4);
    size_t zbytes = off;  // zero [flag, deg, cursor] in one memset
    int* offs = (int*)alloc((size_t)(N_NODES + 1) * 4);
    int* bsum = (int*)alloc(256 * 4);
    int* csr_src = (int*)alloc((size_t)N_EDGES * 4);
    float* csr_w = (float*)alloc((size_t)N_EDGES * 4);
    float* dinv = (float*)alloc((size_t)N_NODES * 4);
    float* B0 = (float*)alloc((size_t)N_NODES * 128 * 4);
    float* B1 = (float*)alloc((size_t)N_NODES * 128 * 4);
    // g6 / xw3 are never live while B1 holds data -> alias into B1 (ws trim)
    float* g6 = B1;
    float* xw3 = B1;

    hipMemsetAsync(d_ws, 0, zbytes, stream);

    k_detect<<<16, 256, 0, stream>>>(E, flag);
    k_count<<<(N_EDGES + 255) / 256, 256, 0, stream>>>(E, flag, deg);
    int nb = (N_NODES + 1023) / 1024;  // 98
    k_scan1<<<nb, 256, 0, stream>>>(deg, offs, bsum, dinv);
    k_scan2<<<1, 256, 0, stream>>>(bsum, nb);
    k_scan3<<<(N_NODES + 255) / 256, 256, 0, stream>>>(offs, bsum);
    k_fill<<<(N_EDGES + 255) / 256, 256, 0, stream>>>(E, flag, dinv, offs, cursor, csr_src, csr_w);

    // layer 0: aggregate (6-wide) then GEMM 6->128 + bias + relu
    k_agg6<<<(N_NODES + 255) / 256, 256, 0, stream>>>(x, sdf, dinv, offs, csr_src, csr_w, g6);
    k_gemm6<<<(N_NODES + 1) / 2, 256, 0, stream>>>(g6, Wl[0], bl[0], B0);

    // layers 1..4: fused aggregate+GEMM+bias+relu, ping-pong B0/B1
    const int FGRID = (N_NODES + 63) / 64;
    k_fused<<<FGRID, 256, 0, stream>>>(B0, Wl[1], bl[1], dinv, offs, csr_src, csr_w, B1);
    k_fused<<<FGRID, 256, 0, stream>>>(B1, Wl[2], bl[2], dinv, offs, csr_src, csr_w, B0);
    k_fused<<<FGRID, 256, 0, stream>>>(B0, Wl[3], bl[3], dinv, offs, csr_src, csr_w, B1);
    k_fused<<<FGRID, 256, 0, stream>>>(B1, Wl[4], bl[4], dinv, offs, csr_src, csr_w, B0);

    // layer 5: GEMM 128->3 then aggregate + bias (no relu)
    k_gemm3<<<(N_NODES + 255) / 256, 256, 0, stream>>>(B0, Wl[5], xw3);
    k_agg3<<<(N_NODES + 255) / 256, 256, 0, stream>>>(xw3, bl[5], dinv, offs, csr_src, csr_w, (float*)d_out);
}

// Round 8
// 608.680 us; speedup vs baseline: 1.2781x; 1.2781x over previous
//
#include <hip/hip_runtime.h>

#define N_NODES 100000
#define N_EDGES 600000
#define IN_CH 5
#define HID 128

typedef __attribute__((ext_vector_type(8))) short short8v;   // 8 bf16 (4 VGPR)
typedef __attribute__((ext_vector_type(4))) float f32x4;     // MFMA acc

__device__ __forceinline__ unsigned short f2bf(float f) {    // fp32 -> bf16 RNE
    unsigned u = __float_as_uint(f);
    unsigned r = (u + 0x7fffu + ((u >> 16) & 1u)) >> 16;
    return (unsigned short)r;
}
__device__ __forceinline__ float bf2f(unsigned short h) { return __uint_as_float(((unsigned)h) << 16); }

// ---------------- edge dtype detection (int64 vs int32 layout) ----------------
__global__ __launch_bounds__(256) void k_detect(const unsigned* __restrict__ E, int* __restrict__ flag) {
    int t = blockIdx.x * blockDim.x + threadIdx.x;
    if (t < 4096) {
        if (E[2 * t + 1] != 0u) atomicOr(flag, 1);
    }
}

__device__ __forceinline__ int edge_elem(const unsigned* __restrict__ E, int elem, int is64) {
    return (int)E[is64 ? (2 * elem) : elem];
}

// ---------------- degree count ----------------
__global__ __launch_bounds__(256) void k_count(const unsigned* __restrict__ E, const int* __restrict__ flag,
                                               int* __restrict__ deg) {
    int e = blockIdx.x * blockDim.x + threadIdx.x;
    int is64 = (*flag == 0) ? 1 : 0;
    if (e < N_EDGES) {
        int d = edge_elem(E, N_EDGES + e, is64);
        atomicAdd(&deg[d], 1);
    }
}

// ---------------- exclusive scan (3-kernel), dinv fused into pass 1 ----------------
__global__ __launch_bounds__(256) void k_scan1(const int* __restrict__ deg, int* __restrict__ offs,
                                               int* __restrict__ bsum, float* __restrict__ dinv) {
    __shared__ int sd[256];
    int t = threadIdx.x;
    int base = blockIdx.x * 1024 + t * 4;
    int v0 = (base + 0 < N_NODES) ? deg[base + 0] : 0;
    int v1 = (base + 1 < N_NODES) ? deg[base + 1] : 0;
    int v2 = (base + 2 < N_NODES) ? deg[base + 2] : 0;
    int v3 = (base + 3 < N_NODES) ? deg[base + 3] : 0;
    if (base + 0 < N_NODES) dinv[base + 0] = rsqrtf((float)v0 + 1.0f);
    if (base + 1 < N_NODES) dinv[base + 1] = rsqrtf((float)v1 + 1.0f);
    if (base + 2 < N_NODES) dinv[base + 2] = rsqrtf((float)v2 + 1.0f);
    if (base + 3 < N_NODES) dinv[base + 3] = rsqrtf((float)v3 + 1.0f);
    sd[t] = v0 + v1 + v2 + v3;
    __syncthreads();
    for (int off = 1; off < 256; off <<= 1) {
        int x = sd[t];
        if (t >= off) x += sd[t - off];
        __syncthreads();
        sd[t] = x;
        __syncthreads();
    }
    int run = (t == 0) ? 0 : sd[t - 1];
    if (base + 0 < N_NODES) offs[base + 0] = run; run += v0;
    if (base + 1 < N_NODES) offs[base + 1] = run; run += v1;
    if (base + 2 < N_NODES) offs[base + 2] = run; run += v2;
    if (base + 3 < N_NODES) offs[base + 3] = run;
    if (t == 255) bsum[blockIdx.x] = sd[255];
}

__global__ __launch_bounds__(256) void k_scan2(int* __restrict__ bsum, int nb) {
    __shared__ int sd[256];
    int t = threadIdx.x;
    sd[t] = (t < nb) ? bsum[t] : 0;
    __syncthreads();
    for (int off = 1; off < 256; off <<= 1) {
        int x = sd[t];
        if (t >= off) x += sd[t - off];
        __syncthreads();
        sd[t] = x;
        __syncthreads();
    }
    if (t < nb) bsum[t] = (t == 0) ? 0 : sd[t - 1];
}

__global__ __launch_bounds__(256) void k_scan3(int* __restrict__ offs, const int* __restrict__ bsum) {
    int i = blockIdx.x * blockDim.x + threadIdx.x;
    if (i < N_NODES) offs[i] += bsum[i >> 10];
    if (i == 0) offs[N_NODES] = N_EDGES;
}

// ---------------- CSR fill ----------------
__global__ __launch_bounds__(256) void k_fill(const unsigned* __restrict__ E, const int* __restrict__ flag,
                                              const float* __restrict__ dinv, const int* __restrict__ offs,
                                              int* __restrict__ cursor, int* __restrict__ csr_src,
                                              float* __restrict__ csr_w) {
    int e = blockIdx.x * blockDim.x + threadIdx.x;
    int is64 = (*flag == 0) ? 1 : 0;
    if (e < N_EDGES) {
        int s = edge_elem(E, e, is64);
        int d = edge_elem(E, N_EDGES + e, is64);
        int p = atomicAdd(&cursor[d], 1);
        int idx = offs[d] + p;
        csr_src[idx] = s;
        csr_w[idx] = dinv[s] * dinv[d];
    }
}

// ---------------- W split: fp32 [128][128] -> bf16 hi/lo in MFMA-fragment layout ----------------
// Wf element (chunk c, coltile ct, lane l, e): k = c*32 + (l>>4)*8 + e, col = ct*16 + (l&15).
// Linear: ((lay*32 + c*8 + ct)*64 + l)*8 + e  -> each fragment is 16 contiguous bytes.
__global__ __launch_bounds__(256) void k_wsplit(const float* __restrict__ W1, const float* __restrict__ W2,
                                                const float* __restrict__ W3, const float* __restrict__ W4,
                                                unsigned short* __restrict__ whi, unsigned short* __restrict__ wlo) {
    int t = blockIdx.x * 256 + threadIdx.x;  // 8192 threads: (lay, c, ct, l)
    if (t >= 8192) return;
    int lay = t >> 11;
    int rem = t & 2047;
    int c = rem >> 9;
    int ct = (rem >> 6) & 7;
    int l = rem & 63;
    const float* W = (lay == 0) ? W1 : (lay == 1) ? W2 : (lay == 2) ? W3 : W4;
    int col = ct * 16 + (l & 15);
    int kbase = c * 32 + ((l >> 4) << 3);
    unsigned short hi[8], lo[8];
#pragma unroll
    for (int e = 0; e < 8; e++) {
        float v = W[(size_t)(kbase + e) * 128 + col];
        hi[e] = f2bf(v);
        lo[e] = f2bf(v - bf2f(hi[e]));
    }
    size_t o = (size_t)t * 8;
    union { unsigned short u[8]; short8v v; } ph, pl;
#pragma unroll
    for (int e = 0; e < 8; e++) { ph.u[e] = hi[e]; pl.u[e] = lo[e]; }
    *(short8v*)&whi[o] = ph.v;
    *(short8v*)&wlo[o] = pl.v;
}

// ---------------- layer 0: aggregate on 6-wide input ----------------
__global__ __launch_bounds__(256) void k_agg6(const float* __restrict__ x, const float* __restrict__ sdf,
                                              const float* __restrict__ dinv, const int* __restrict__ offs,
                                              const int* __restrict__ csr_src, const float* __restrict__ csr_w,
                                              float* __restrict__ g) {
    int i = blockIdx.x * blockDim.x + threadIdx.x;
    if (i >= N_NODES) return;
    float dn = dinv[i];
    float dn2 = dn * dn;
    float a[6];
#pragma unroll
    for (int f = 0; f < IN_CH; f++) a[f] = dn2 * x[i * IN_CH + f];
    a[5] = dn2 * sdf[i];
    int e0 = offs[i], e1 = offs[i + 1];
    for (int e = e0; e < e1; e++) {
        int s = csr_src[e];
        float w = csr_w[e];
#pragma unroll
        for (int f = 0; f < IN_CH; f++) a[f] += w * x[s * IN_CH + f];
        a[5] += w * sdf[s];
    }
#pragma unroll
    for (int f = 0; f < 6; f++) g[i * 6 + f] = a[f];
}

// ---------------- layer 0 GEMM: [N,6] @ [6,128] + b, relu ----------------
__global__ __launch_bounds__(256) void k_gemm6(const float* __restrict__ g, const float* __restrict__ W,
                                               const float* __restrict__ b, float* __restrict__ out) {
    __shared__ float Ws[6 * 128];
    __shared__ float bs[128];
    int t = threadIdx.x;
    for (int j = t; j < 768; j += 256) Ws[j] = W[j];
    if (t < 128) bs[t] = b[t];
    __syncthreads();
    int node = blockIdx.x * 2 + (t >> 7);
    int f = t & 127;
    if (node >= N_NODES) return;
    float acc = bs[f];
#pragma unroll
    for (int k = 0; k < 6; k++) acc += g[node * 6 + k] * Ws[k * 128 + f];
    out[node * 128 + f] = fmaxf(acc, 0.0f);
}

// ---------------- hidden GEMM via MFMA, 4-term split-bf16 (fp32-accurate) ----------------
// No LDS, no barriers. Block = 4 waves; wave owns 16 rows x 128 cols.
// Per k-chunk (K=32): A-frag = 2 coalesced float4 loads of own rows + in-reg
// bf16 hi/lo split; B-frags = coalesced 16B/lane loads from pre-split Wf.
// acc[ct] += Ah*Bh + Al*Bh + Ah*Bl + Al*Bl  (error ~2^-18, fp32-class).
__global__ __launch_bounds__(256) void k_gemm128m(const float* __restrict__ H, const unsigned short* __restrict__ whi,
                                                  const unsigned short* __restrict__ wlo, float* __restrict__ out) {
    int t = threadIdx.x;
    int wv = t >> 6;
    int l = t & 63;
    int row0 = blockIdx.x * 64 + wv * 16;
    int arow = row0 + (l & 15);
    if (arow >= N_NODES) arow = N_NODES - 1;  // clamp loads; stores guarded

    f32x4 acc[8];
#pragma unroll
    for (int ct = 0; ct < 8; ct++) acc[ct] = (f32x4){0.f, 0.f, 0.f, 0.f};

    for (int c = 0; c < 4; c++) {
        int k0 = c * 32 + ((l >> 4) << 3);
        const float4* ap = (const float4*)&H[(size_t)arow * 128 + k0];
        float4 a0 = ap[0], a1 = ap[1];
        float av[8] = {a0.x, a0.y, a0.z, a0.w, a1.x, a1.y, a1.z, a1.w};
        union { unsigned short u[8]; short8v v; } ah, al;
#pragma unroll
        for (int e = 0; e < 8; e++) {
            unsigned short h = f2bf(av[e]);
            ah.u[e] = h;
            al.u[e] = f2bf(av[e] - bf2f(h));
        }
        const short8v* bh = (const short8v*)&whi[((size_t)(c * 8) * 64 + l) * 8];
        const short8v* bl = (const short8v*)&wlo[((size_t)(c * 8) * 64 + l) * 8];
#pragma unroll
        for (int ct = 0; ct < 8; ct++) {
            short8v vbh = bh[ct * 64];
            short8v vbl = bl[ct * 64];
            acc[ct] = __builtin_amdgcn_mfma_f32_16x16x32_bf16(ah.v, vbh, acc[ct], 0, 0, 0);
            acc[ct] = __builtin_amdgcn_mfma_f32_16x16x32_bf16(al.v, vbh, acc[ct], 0, 0, 0);
            acc[ct] = __builtin_amdgcn_mfma_f32_16x16x32_bf16(ah.v, vbl, acc[ct], 0, 0, 0);
            acc[ct] = __builtin_amdgcn_mfma_f32_16x16x32_bf16(al.v, vbl, acc[ct], 0, 0, 0);
        }
    }

    // C/D layout: col = lane&15, row = (lane>>4)*4 + reg
    int rbase = row0 + ((l >> 4) << 2);
    int col = l & 15;
#pragma unroll
    for (int ct = 0; ct < 8; ct++) {
#pragma unroll
        for (int r = 0; r < 4; r++) {
            int row = rbase + r;
            if (row < N_NODES) out[(size_t)row * 128 + ct * 16 + col] = acc[ct][r];
        }
    }
}

// ---------------- hidden aggregation: 16-lane group per node, 2-edge unroll ----------------
// Non-temporal output stores: don't evict the gather target (xw) from L2.
__global__ __launch_bounds__(256) void k_agg128(const float* __restrict__ xw, const float* __restrict__ bias,
                                                const float* __restrict__ dinv, const int* __restrict__ offs,
                                                const int* __restrict__ csr_src, const float* __restrict__ csr_w,
                                                float* __restrict__ out) {
    int t = threadIdx.x;
    int grp = t >> 4;   // 0..15
    int sub = t & 15;   // floats sub*8 .. sub*8+7
    int node = blockIdx.x * 16 + grp;
    if (node >= N_NODES) return;
    const float4* xw4 = (const float4*)xw;  // row = 32 float4
    float dn = dinv[node];
    float dn2 = dn * dn;
    size_t self = (size_t)node * 32 + sub * 2;
    float4 v0 = xw4[self], v1 = xw4[self + 1];
    float4 aA0, aA1, aB0, aB1;
    aA0.x = dn2 * v0.x; aA0.y = dn2 * v0.y; aA0.z = dn2 * v0.z; aA0.w = dn2 * v0.w;
    aA1.x = dn2 * v1.x; aA1.y = dn2 * v1.y; aA1.z = dn2 * v1.z; aA1.w = dn2 * v1.w;
    aB0 = make_float4(0.f, 0.f, 0.f, 0.f);
    aB1 = make_float4(0.f, 0.f, 0.f, 0.f);
    int e0 = offs[node], e1 = offs[node + 1];
    int e = e0;
    for (; e + 1 < e1; e += 2) {
        int s0 = csr_src[e];
        int s1 = csr_src[e + 1];
        float w0 = csr_w[e];
        float w1 = csr_w[e + 1];
        size_t r0 = (size_t)s0 * 32 + sub * 2;
        size_t r1 = (size_t)s1 * 32 + sub * 2;
        float4 u00 = xw4[r0], u01 = xw4[r0 + 1];
        float4 u10 = xw4[r1], u11 = xw4[r1 + 1];
        aA0.x += w0 * u00.x; aA0.y += w0 * u00.y; aA0.z += w0 * u00.z; aA0.w += w0 * u00.w;
        aA1.x += w0 * u01.x; aA1.y += w0 * u01.y; aA1.z += w0 * u01.z; aA1.w += w0 * u01.w;
        aB0.x += w1 * u10.x; aB0.y += w1 * u10.y; aB0.z += w1 * u10.z; aB0.w += w1 * u10.w;
        aB1.x += w1 * u11.x; aB1.y += w1 * u11.y; aB1.z += w1 * u11.z; aB1.w += w1 * u11.w;
    }
    if (e < e1) {
        int s0 = csr_src[e];
        float w0 = csr_w[e];
        size_t r0 = (size_t)s0 * 32 + sub * 2;
        float4 u00 = xw4[r0], u01 = xw4[r0 + 1];
        aA0.x += w0 * u00.x; aA0.y += w0 * u00.y; aA0.z += w0 * u00.z; aA0.w += w0 * u00.w;
        aA1.x += w0 * u01.x; aA1.y += w0 * u01.y; aA1.z += w0 * u01.z; aA1.w += w0 * u01.w;
    }
    float4 b0 = ((const float4*)bias)[sub * 2];
    float4 b1 = ((const float4*)bias)[sub * 2 + 1];
    f32x4 o0, o1;
    o0[0] = fmaxf(aA0.x + aB0.x + b0.x, 0.0f);
    o0[1] = fmaxf(aA0.y + aB0.y + b0.y, 0.0f);
    o0[2] = fmaxf(aA0.z + aB0.z + b0.z, 0.0f);
    o0[3] = fmaxf(aA0.w + aB0.w + b0.w, 0.0f);
    o1[0] = fmaxf(aA1.x + aB1.x + b1.x, 0.0f);
    o1[1] = fmaxf(aA1.y + aB1.y + b1.y, 0.0f);
    o1[2] = fmaxf(aA1.z + aB1.z + b1.z, 0.0f);
    o1[3] = fmaxf(aA1.w + aB1.w + b1.w, 0.0f);
    f32x4* o = (f32x4*)out;
    __builtin_nontemporal_store(o0, &o[self]);
    __builtin_nontemporal_store(o1, &o[self + 1]);
}

// ---------------- final GEMM: [N,128] @ [128,3] ----------------
__global__ __launch_bounds__(256) void k_gemm3(const float* __restrict__ H, const float* __restrict__ W,
                                               float* __restrict__ out) {
    __shared__ float Ws[128 * 3];
    int t = threadIdx.x;
    for (int j = t; j < 384; j += 256) Ws[j] = W[j];
    __syncthreads();
    int i = blockIdx.x * 256 + t;
    if (i >= N_NODES) return;
    float a0 = 0.f, a1 = 0.f, a2 = 0.f;
#pragma unroll
    for (int k = 0; k < 128; k += 4) {
        float4 v = *(const float4*)&H[(size_t)i * 128 + k];
        a0 += v.x * Ws[(k + 0) * 3 + 0] + v.y * Ws[(k + 1) * 3 + 0] + v.z * Ws[(k + 2) * 3 + 0] + v.w * Ws[(k + 3) * 3 + 0];
        a1 += v.x * Ws[(k + 0) * 3 + 1] + v.y * Ws[(k + 1) * 3 + 1] + v.z * Ws[(k + 2) * 3 + 1] + v.w * Ws[(k + 3) * 3 + 1];
        a2 += v.x * Ws[(k + 0) * 3 + 2] + v.y * Ws[(k + 1) * 3 + 2] + v.z * Ws[(k + 2) * 3 + 2] + v.w * Ws[(k + 3) * 3 + 2];
    }
    out[(size_t)i * 3 + 0] = a0;
    out[(size_t)i * 3 + 1] = a1;
    out[(size_t)i * 3 + 2] = a2;
}

// ---------------- final aggregation on 3 feats + bias (no relu) ----------------
__global__ __launch_bounds__(256) void k_agg3(const float* __restrict__ xw3, const float* __restrict__ b,
                                              const float* __restrict__ dinv, const int* __restrict__ offs,
                                              const int* __restrict__ csr_src, const float* __restrict__ csr_w,
                                              float* __restrict__ out) {
    int i = blockIdx.x * blockDim.x + threadIdx.x;
    if (i >= N_NODES) return;
    float dn = dinv[i];
    float dn2 = dn * dn;
    float a0 = dn2 * xw3[(size_t)i * 3 + 0];
    float a1 = dn2 * xw3[(size_t)i * 3 + 1];
    float a2 = dn2 * xw3[(size_t)i * 3 + 2];
    int e0 = offs[i], e1 = offs[i + 1];
    for (int e = e0; e < e1; e++) {
        int s = csr_src[e];
        float w = csr_w[e];
        a0 += w * xw3[(size_t)s * 3 + 0];
        a1 += w * xw3[(size_t)s * 3 + 1];
        a2 += w * xw3[(size_t)s * 3 + 2];
    }
    out[(size_t)i * 3 + 0] = a0 + b[0];
    out[(size_t)i * 3 + 1] = a1 + b[1];
    out[(size_t)i * 3 + 2] = a2 + b[2];
}

extern "C" void kernel_launch(void* const* d_in, const int* in_sizes, int n_in,
                              void* d_out, int out_size, void* d_ws, size_t ws_size,
                              hipStream_t stream) {
    const float* x = (const float*)d_in[0];
    const float* sdf = (const float*)d_in[1];
    const unsigned* E = (const unsigned*)d_in[2];
    const float* Wl[6];
    const float* bl[6];
    for (int l = 0; l < 6; l++) {
        Wl[l] = (const float*)d_in[3 + 2 * l];
        bl[l] = (const float*)d_in[4 + 2 * l];
    }

    char* ws = (char*)d_ws;
    size_t off = 0;
    auto alloc = [&](size_t bytes) -> void* {
        void* p = ws + off;
        off += (bytes + 255) / 256 * 256;
        return p;
    };
    int* flag = (int*)alloc(4);
    int* deg = (int*)alloc((size_t)N_NODES * 4);
    int* cursor = (int*)alloc((size_t)N_NODES * 4);
    size_t zbytes = off;  // zero [flag, deg, cursor] in one memset
    int* offs = (int*)alloc((size_t)(N_NODES + 1) * 4);
    int* bsum = (int*)alloc(256 * 4);
    int* csr_src = (int*)alloc((size_t)N_EDGES * 4);
    float* csr_w = (float*)alloc((size_t)N_EDGES * 4);
    float* dinv = (float*)alloc((size_t)N_NODES * 4);
    unsigned short* whi = (unsigned short*)alloc((size_t)4 * 16384 * 2);  // 4 layers W hi (frag layout)
    unsigned short* wlo = (unsigned short*)alloc((size_t)4 * 16384 * 2);
    float* B0 = (float*)alloc((size_t)N_NODES * 128 * 4);
    float* B1 = (float*)alloc((size_t)N_NODES * 128 * 4);
    // g6 / xw3 are never live while B1 holds data -> alias into B1 (ws trim)
    float* g6 = B1;
    float* xw3 = B1;

    hipMemsetAsync(d_ws, 0, zbytes, stream);

    k_detect<<<16, 256, 0, stream>>>(E, flag);
    k_count<<<(N_EDGES + 255) / 256, 256, 0, stream>>>(E, flag, deg);
    int nb = (N_NODES + 1023) / 1024;  // 98
    k_scan1<<<nb, 256, 0, stream>>>(deg, offs, bsum, dinv);
    k_scan2<<<1, 256, 0, stream>>>(bsum, nb);
    k_scan3<<<(N_NODES + 255) / 256, 256, 0, stream>>>(offs, bsum);
    k_fill<<<(N_EDGES + 255) / 256, 256, 0, stream>>>(E, flag, dinv, offs, cursor, csr_src, csr_w);
    k_wsplit<<<32, 256, 0, stream>>>(Wl[1], Wl[2], Wl[3], Wl[4], whi, wlo);

    // layer 0: aggregate (6-wide) then GEMM 6->128 + bias + relu
    k_agg6<<<(N_NODES + 255) / 256, 256, 0, stream>>>(x, sdf, dinv, offs, csr_src, csr_w, g6);
    k_gemm6<<<(N_NODES + 1) / 2, 256, 0, stream>>>(g6, Wl[0], bl[0], B0);

    // layers 1..4: MFMA GEMM 128->128 then aggregate + bias + relu
    const int GGRID = (N_NODES + 63) / 64;
    for (int l = 1; l <= 4; l++) {
        size_t lo = (size_t)(l - 1) * 16384;
        k_gemm128m<<<GGRID, 256, 0, stream>>>(B0, whi + lo, wlo + lo, B1);
        k_agg128<<<(N_NODES + 15) / 16, 256, 0, stream>>>(B1, bl[l], dinv, offs, csr_src, csr_w, B0);
    }

    // layer 5: GEMM 128->3 then aggregate + bias (no relu)
    k_gemm3<<<(N_NODES + 255) / 256, 256, 0, stream>>>(B0, Wl[5], xw3);
    k_agg3<<<(N_NODES + 255) / 256, 256, 0, stream>>>(xw3, bl[5], dinv, offs, csr_src, csr_w, (float*)d_out);
}

// Round 12
// 599.696 us; speedup vs baseline: 1.2972x; 1.0150x over previous
//
#include <hip/hip_runtime.h>

#define N_NODES 100000
#define N_EDGES 600000
#define IN_CH 5
#define HID 128

typedef __attribute__((ext_vector_type(8))) short short8v;   // 8 bf16 (4 VGPR)
typedef __attribute__((ext_vector_type(4))) float f32x4;     // MFMA acc

__device__ __forceinline__ unsigned short f2bf(float f) {    // fp32 -> bf16 RNE
    unsigned u = __float_as_uint(f);
    unsigned r = (u + 0x7fffu + ((u >> 16) & 1u)) >> 16;
    return (unsigned short)r;
}
__device__ __forceinline__ float bf2f(unsigned short h) { return __uint_as_float(((unsigned)h) << 16); }

// ---------------- edge dtype detection (int64 vs int32 layout) ----------------
__global__ __launch_bounds__(256) void k_detect(const unsigned* __restrict__ E, int* __restrict__ flag) {
    int t = blockIdx.x * blockDim.x + threadIdx.x;
    if (t < 4096) {
        if (E[2 * t + 1] != 0u) atomicOr(flag, 1);
    }
}

__device__ __forceinline__ int edge_elem(const unsigned* __restrict__ E, int elem, int is64) {
    return (int)E[is64 ? (2 * elem) : elem];
}

// ---------------- degree count ----------------
__global__ __launch_bounds__(256) void k_count(const unsigned* __restrict__ E, const int* __restrict__ flag,
                                               int* __restrict__ deg) {
    int e = blockIdx.x * blockDim.x + threadIdx.x;
    int is64 = (*flag == 0) ? 1 : 0;
    if (e < N_EDGES) {
        int d = edge_elem(E, N_EDGES + e, is64);
        atomicAdd(&deg[d], 1);
    }
}

// ---------------- exclusive scan (3-kernel), dinv fused into pass 1 ----------------
__global__ __launch_bounds__(256) void k_scan1(const int* __restrict__ deg, int* __restrict__ offs,
                                               int* __restrict__ bsum, float* __restrict__ dinv) {
    __shared__ int sd[256];
    int t = threadIdx.x;
    int base = blockIdx.x * 1024 + t * 4;
    int v0 = (base + 0 < N_NODES) ? deg[base + 0] : 0;
    int v1 = (base + 1 < N_NODES) ? deg[base + 1] : 0;
    int v2 = (base + 2 < N_NODES) ? deg[base + 2] : 0;
    int v3 = (base + 3 < N_NODES) ? deg[base + 3] : 0;
    if (base + 0 < N_NODES) dinv[base + 0] = rsqrtf((float)v0 + 1.0f);
    if (base + 1 < N_NODES) dinv[base + 1] = rsqrtf((float)v1 + 1.0f);
    if (base + 2 < N_NODES) dinv[base + 2] = rsqrtf((float)v2 + 1.0f);
    if (base + 3 < N_NODES) dinv[base + 3] = rsqrtf((float)v3 + 1.0f);
    sd[t] = v0 + v1 + v2 + v3;
    __syncthreads();
    for (int off = 1; off < 256; off <<= 1) {
        int x = sd[t];
        if (t >= off) x += sd[t - off];
        __syncthreads();
        sd[t] = x;
        __syncthreads();
    }
    int run = (t == 0) ? 0 : sd[t - 1];
    if (base + 0 < N_NODES) offs[base + 0] = run; run += v0;
    if (base + 1 < N_NODES) offs[base + 1] = run; run += v1;
    if (base + 2 < N_NODES) offs[base + 2] = run; run += v2;
    if (base + 3 < N_NODES) offs[base + 3] = run;
    if (t == 255) bsum[blockIdx.x] = sd[255];
}

__global__ __launch_bounds__(256) void k_scan2(int* __restrict__ bsum, int nb) {
    __shared__ int sd[256];
    int t = threadIdx.x;
    sd[t] = (t < nb) ? bsum[t] : 0;
    __syncthreads();
    for (int off = 1; off < 256; off <<= 1) {
        int x = sd[t];
        if (t >= off) x += sd[t - off];
        __syncthreads();
        sd[t] = x;
        __syncthreads();
    }
    if (t < nb) bsum[t] = (t == 0) ? 0 : sd[t - 1];
}

__global__ __launch_bounds__(256) void k_scan3(int* __restrict__ offs, const int* __restrict__ bsum) {
    int i = blockIdx.x * blockDim.x + threadIdx.x;
    if (i < N_NODES) offs[i] += bsum[i >> 10];
    if (i == 0) offs[N_NODES] = N_EDGES;
}

// ---------------- CSR fill ----------------
__global__ __launch_bounds__(256) void k_fill(const unsigned* __restrict__ E, const int* __restrict__ flag,
                                              const float* __restrict__ dinv, const int* __restrict__ offs,
                                              int* __restrict__ cursor, int* __restrict__ csr_src,
                                              float* __restrict__ csr_w) {
    int e = blockIdx.x * blockDim.x + threadIdx.x;
    int is64 = (*flag == 0) ? 1 : 0;
    if (e < N_EDGES) {
        int s = edge_elem(E, e, is64);
        int d = edge_elem(E, N_EDGES + e, is64);
        int p = atomicAdd(&cursor[d], 1);
        int idx = offs[d] + p;
        csr_src[idx] = s;
        csr_w[idx] = dinv[s] * dinv[d];
    }
}

// ---------------- W split: fp32 [128][128] -> bf16 hi/lo in MFMA-fragment layout ----------------
// Wf element (chunk c, coltile ct, lane l, e): k = c*32 + (l>>4)*8 + e, col = ct*16 + (l&15).
// Linear: ((lay*32 + c*8 + ct)*64 + l)*8 + e  -> each fragment is 16 contiguous bytes.
__global__ __launch_bounds__(256) void k_wsplit(const float* __restrict__ W1, const float* __restrict__ W2,
                                                const float* __restrict__ W3, const float* __restrict__ W4,
                                                unsigned short* __restrict__ whi, unsigned short* __restrict__ wlo) {
    int t = blockIdx.x * 256 + threadIdx.x;  // 8192 threads: (lay, c, ct, l)
    if (t >= 8192) return;
    int lay = t >> 11;
    int rem = t & 2047;
    int c = rem >> 9;
    int ct = (rem >> 6) & 7;
    int l = rem & 63;
    const float* W = (lay == 0) ? W1 : (lay == 1) ? W2 : (lay == 2) ? W3 : W4;
    int col = ct * 16 + (l & 15);
    int kbase = c * 32 + ((l >> 4) << 3);
    unsigned short hi[8], lo[8];
#pragma unroll
    for (int e = 0; e < 8; e++) {
        float v = W[(size_t)(kbase + e) * 128 + col];
        hi[e] = f2bf(v);
        lo[e] = f2bf(v - bf2f(hi[e]));
    }
    size_t o = (size_t)t * 8;
    union { unsigned short u[8]; short8v v; } ph, pl;
#pragma unroll
    for (int e = 0; e < 8; e++) { ph.u[e] = hi[e]; pl.u[e] = lo[e]; }
    *(short8v*)&whi[o] = ph.v;
    *(short8v*)&wlo[o] = pl.v;
}

// ---------------- layer 0: aggregate on 6-wide input ----------------
__global__ __launch_bounds__(256) void k_agg6(const float* __restrict__ x, const float* __restrict__ sdf,
                                              const float* __restrict__ dinv, const int* __restrict__ offs,
                                              const int* __restrict__ csr_src, const float* __restrict__ csr_w,
                                              float* __restrict__ g) {
    int i = blockIdx.x * blockDim.x + threadIdx.x;
    if (i >= N_NODES) return;
    float dn = dinv[i];
    float dn2 = dn * dn;
    float a[6];
#pragma unroll
    for (int f = 0; f < IN_CH; f++) a[f] = dn2 * x[i * IN_CH + f];
    a[5] = dn2 * sdf[i];
    int e0 = offs[i], e1 = offs[i + 1];
    for (int e = e0; e < e1; e++) {
        int s = csr_src[e];
        float w = csr_w[e];
#pragma unroll
        for (int f = 0; f < IN_CH; f++) a[f] += w * x[s * IN_CH + f];
        a[5] += w * sdf[s];
    }
#pragma unroll
    for (int f = 0; f < 6; f++) g[i * 6 + f] = a[f];
}

// ---------------- layer 0 GEMM: [N,6] @ [6,128] + b, relu ----------------
__global__ __launch_bounds__(256) void k_gemm6(const float* __restrict__ g, const float* __restrict__ W,
                                               const float* __restrict__ b, float* __restrict__ out) {
    __shared__ float Ws[6 * 128];
    __shared__ float bs[128];
    int t = threadIdx.x;
    for (int j = t; j < 768; j += 256) Ws[j] = W[j];
    if (t < 128) bs[t] = b[t];
    __syncthreads();
    int node = blockIdx.x * 2 + (t >> 7);
    int f = t & 127;
    if (node >= N_NODES) return;
    float acc = bs[f];
#pragma unroll
    for (int k = 0; k < 6; k++) acc += g[node * 6 + k] * Ws[k * 128 + f];
    out[node * 128 + f] = fmaxf(acc, 0.0f);
}

// ---------------- hidden GEMM via MFMA, 3-term split-bf16 (fp32-class accuracy) ----------------
// No LDS, no barriers. Wave owns 16 rows x 128 cols. A lane's row is constant
// across k-chunks -> ALL 8 A-float4 loads issue up-front (one wait), convert
// once; inner loop is then L2-hot B-frag loads + MFMA only.
__global__ __launch_bounds__(256) void k_gemm128m(const float* __restrict__ H, const unsigned short* __restrict__ whi,
                                                  const unsigned short* __restrict__ wlo, float* __restrict__ out) {
    int t = threadIdx.x;
    int wv = t >> 6;
    int l = t & 63;
    int row0 = blockIdx.x * 64 + wv * 16;
    int arow = row0 + (l & 15);
    if (arow >= N_NODES) arow = N_NODES - 1;  // clamp loads; stores guarded

    // ---- load entire A strip for this lane: 4 chunks x 8 floats ----
    const float4* ap = (const float4*)&H[(size_t)arow * 128 + ((l >> 4) << 3)];
    float4 araw[8];
#pragma unroll
    for (int c = 0; c < 4; c++) {
        araw[2 * c] = ap[c * 8];
        araw[2 * c + 1] = ap[c * 8 + 1];
    }
    union { unsigned short u[8]; short8v v; } ah[4], al[4];
#pragma unroll
    for (int c = 0; c < 4; c++) {
        float av[8] = {araw[2 * c].x, araw[2 * c].y, araw[2 * c].z, araw[2 * c].w,
                       araw[2 * c + 1].x, araw[2 * c + 1].y, araw[2 * c + 1].z, araw[2 * c + 1].w};
#pragma unroll
        for (int e = 0; e < 8; e++) {
            unsigned short h = f2bf(av[e]);
            ah[c].u[e] = h;
            al[c].u[e] = f2bf(av[e] - bf2f(h));
        }
    }

    f32x4 acc[8];
#pragma unroll
    for (int ct = 0; ct < 8; ct++) acc[ct] = (f32x4){0.f, 0.f, 0.f, 0.f};

#pragma unroll
    for (int c = 0; c < 4; c++) {
        const short8v* bh = (const short8v*)&whi[((size_t)(c * 8) * 64 + l) * 8];
        const short8v* bl = (const short8v*)&wlo[((size_t)(c * 8) * 64 + l) * 8];
#pragma unroll
        for (int ct = 0; ct < 8; ct++) {
            short8v vbh = bh[ct * 64];
            short8v vbl = bl[ct * 64];
            acc[ct] = __builtin_amdgcn_mfma_f32_16x16x32_bf16(ah[c].v, vbh, acc[ct], 0, 0, 0);
            acc[ct] = __builtin_amdgcn_mfma_f32_16x16x32_bf16(al[c].v, vbh, acc[ct], 0, 0, 0);
            acc[ct] = __builtin_amdgcn_mfma_f32_16x16x32_bf16(ah[c].v, vbl, acc[ct], 0, 0, 0);
        }
    }

    // C/D layout: col = lane&15, row = (lane>>4)*4 + reg
    int rbase = row0 + ((l >> 4) << 2);
    int col = l & 15;
#pragma unroll
    for (int ct = 0; ct < 8; ct++) {
#pragma unroll
        for (int r = 0; r < 4; r++) {
            int row = rbase + r;
            if (row < N_NODES) out[(size_t)row * 128 + ct * 16 + col] = acc[ct][r];
        }
    }
}

// ---------------- hidden aggregation: 16-lane group per node, 4-edge unroll ----------------
// 4 independent gather rows + 4 accumulator pairs per group -> 2 KB outstanding
// per group, no dependent-FMA serialization. Non-temporal output stores.
__global__ __launch_bounds__(256) void k_agg128(const float* __restrict__ xw, const float* __restrict__ bias,
                                                const float* __restrict__ dinv, const int* __restrict__ offs,
                                                const int* __restrict__ csr_src, const float* __restrict__ csr_w,
                                                float* __restrict__ out) {
    int t = threadIdx.x;
    int grp = t >> 4;   // 0..15
    int sub = t & 15;   // floats sub*8 .. sub*8+7
    int node = blockIdx.x * 16 + grp;
    if (node >= N_NODES) return;
    const float4* xw4 = (const float4*)xw;  // row = 32 float4
    float dn = dinv[node];
    float dn2 = dn * dn;
    size_t self = (size_t)node * 32 + sub * 2;
    float4 v0 = xw4[self], v1 = xw4[self + 1];
    float4 aA0, aA1, aB0, aB1, aC0, aC1, aD0, aD1;
    aA0.x = dn2 * v0.x; aA0.y = dn2 * v0.y; aA0.z = dn2 * v0.z; aA0.w = dn2 * v0.w;
    aA1.x = dn2 * v1.x; aA1.y = dn2 * v1.y; aA1.z = dn2 * v1.z; aA1.w = dn2 * v1.w;
    aB0 = make_float4(0.f, 0.f, 0.f, 0.f); aB1 = aB0;
    aC0 = aB0; aC1 = aB0; aD0 = aB0; aD1 = aB0;
    int e0 = offs[node], e1 = offs[node + 1];
    int e = e0;
    for (; e + 3 < e1; e += 4) {
        int s0 = csr_src[e], s1 = csr_src[e + 1], s2 = csr_src[e + 2], s3 = csr_src[e + 3];
        float w0 = csr_w[e], w1 = csr_w[e + 1], w2 = csr_w[e + 2], w3 = csr_w[e + 3];
        size_t r0 = (size_t)s0 * 32 + sub * 2;
        size_t r1 = (size_t)s1 * 32 + sub * 2;
        size_t r2 = (size_t)s2 * 32 + sub * 2;
        size_t r3 = (size_t)s3 * 32 + sub * 2;
        float4 u00 = xw4[r0], u01 = xw4[r0 + 1];
        float4 u10 = xw4[r1], u11 = xw4[r1 + 1];
        float4 u20 = xw4[r2], u21 = xw4[r2 + 1];
        float4 u30 = xw4[r3], u31 = xw4[r3 + 1];
        aA0.x += w0 * u00.x; aA0.y += w0 * u00.y; aA0.z += w0 * u00.z; aA0.w += w0 * u00.w;
        aA1.x += w0 * u01.x; aA1.y += w0 * u01.y; aA1.z += w0 * u01.z; aA1.w += w0 * u01.w;
        aB0.x += w1 * u10.x; aB0.y += w1 * u10.y; aB0.z += w1 * u10.z; aB0.w += w1 * u10.w;
        aB1.x += w1 * u11.x; aB1.y += w1 * u11.y; aB1.z += w1 * u11.z; aB1.w += w1 * u11.w;
        aC0.x += w2 * u20.x; aC0.y += w2 * u20.y; aC0.z += w2 * u20.z; aC0.w += w2 * u20.w;
        aC1.x += w2 * u21.x; aC1.y += w2 * u21.y; aC1.z += w2 * u21.z; aC1.w += w2 * u21.w;
        aD0.x += w3 * u30.x; aD0.y += w3 * u30.y; aD0.z += w3 * u30.z; aD0.w += w3 * u30.w;
        aD1.x += w3 * u31.x; aD1.y += w3 * u31.y; aD1.z += w3 * u31.z; aD1.w += w3 * u31.w;
    }
    for (; e < e1; e++) {
        int s0 = csr_src[e];
        float w0 = csr_w[e];
        size_t r0 = (size_t)s0 * 32 + sub * 2;
        float4 u00 = xw4[r0], u01 = xw4[r0 + 1];
        aA0.x += w0 * u00.x; aA0.y += w0 * u00.y; aA0.z += w0 * u00.z; aA0.w += w0 * u00.w;
        aA1.x += w0 * u01.x; aA1.y += w0 * u01.y; aA1.z += w0 * u01.z; aA1.w += w0 * u01.w;
    }
    float4 b0 = ((const float4*)bias)[sub * 2];
    float4 b1 = ((const float4*)bias)[sub * 2 + 1];
    f32x4 o0, o1;
    o0[0] = fmaxf(aA0.x + aB0.x + aC0.x + aD0.x + b0.x, 0.0f);
    o0[1] = fmaxf(aA0.y + aB0.y + aC0.y + aD0.y + b0.y, 0.0f);
    o0[2] = fmaxf(aA0.z + aB0.z + aC0.z + aD0.z + b0.z, 0.0f);
    o0[3] = fmaxf(aA0.w + aB0.w + aC0.w + aD0.w + b0.w, 0.0f);
    o1[0] = fmaxf(aA1.x + aB1.x + aC1.x + aD1.x + b1.x, 0.0f);
    o1[1] = fmaxf(aA1.y + aB1.y + aC1.y + aD1.y + b1.y, 0.0f);
    o1[2] = fmaxf(aA1.z + aB1.z + aC1.z + aD1.z + b1.z, 0.0f);
    o1[3] = fmaxf(aA1.w + aB1.w + aC1.w + aD1.w + b1.w, 0.0f);
    f32x4* o = (f32x4*)out;
    __builtin_nontemporal_store(o0, &o[self]);
    __builtin_nontemporal_store(o1, &o[self + 1]);
}

// ---------------- final GEMM: [N,128] @ [128,3] ----------------
__global__ __launch_bounds__(256) void k_gemm3(const float* __restrict__ H, const float* __restrict__ W,
                                               float* __restrict__ out) {
    __shared__ float Ws[128 * 3];
    int t = threadIdx.x;
    for (int j = t; j < 384; j += 256) Ws[j] = W[j];
    __syncthreads();
    int i = blockIdx.x * 256 + t;
    if (i >= N_NODES) return;
    float a0 = 0.f, a1 = 0.f, a2 = 0.f;
#pragma unroll
    for (int k = 0; k < 128; k += 4) {
        float4 v = *(const float4*)&H[(size_t)i * 128 + k];
        a0 += v.x * Ws[(k + 0) * 3 + 0] + v.y * Ws[(k + 1) * 3 + 0] + v.z * Ws[(k + 2) * 3 + 0] + v.w * Ws[(k + 3) * 3 + 0];
        a1 += v.x * Ws[(k + 0) * 3 + 1] + v.y * Ws[(k + 1) * 3 + 1] + v.z * Ws[(k + 2) * 3 + 1] + v.w * Ws[(k + 3) * 3 + 1];
        a2 += v.x * Ws[(k + 0) * 3 + 2] + v.y * Ws[(k + 1) * 3 + 2] + v.z * Ws[(k + 2) * 3 + 2] + v.w * Ws[(k + 3) * 3 + 2];
    }
    out[(size_t)i * 3 + 0] = a0;
    out[(size_t)i * 3 + 1] = a1;
    out[(size_t)i * 3 + 2] = a2;
}

// ---------------- final aggregation on 3 feats + bias (no relu) ----------------
__global__ __launch_bounds__(256) void k_agg3(const float* __restrict__ xw3, const float* __restrict__ b,
                                              const float* __restrict__ dinv, const int* __restrict__ offs,
                                              const int* __restrict__ csr_src, const float* __restrict__ csr_w,
                                              float* __restrict__ out) {
    int i = blockIdx.x * blockDim.x + threadIdx.x;
    if (i >= N_NODES) return;
    float dn = dinv[i];
    float dn2 = dn * dn;
    float a0 = dn2 * xw3[(size_t)i * 3 + 0];
    float a1 = dn2 * xw3[(size_t)i * 3 + 1];
    float a2 = dn2 * xw3[(size_t)i * 3 + 2];
    int e0 = offs[i], e1 = offs[i + 1];
    for (int e = e0; e < e1; e++) {
        int s = csr_src[e];
        float w = csr_w[e];
        a0 += w * xw3[(size_t)s * 3 + 0];
        a1 += w * xw3[(size_t)s * 3 + 1];
        a2 += w * xw3[(size_t)s * 3 + 2];
    }
    out[(size_t)i * 3 + 0] = a0 + b[0];
    out[(size_t)i * 3 + 1] = a1 + b[1];
    out[(size_t)i * 3 + 2] = a2 + b[2];
}

extern "C" void kernel_launch(void* const* d_in, const int* in_sizes, int n_in,
                              void* d_out, int out_size, void* d_ws, size_t ws_size,
                              hipStream_t stream) {
    const float* x = (const float*)d_in[0];
    const float* sdf = (const float*)d_in[1];
    const unsigned* E = (const unsigned*)d_in[2];
    const float* Wl[6];
    const float* bl[6];
    for (int l = 0; l < 6; l++) {
        Wl[l] = (const float*)d_in[3 + 2 * l];
        bl[l] = (const float*)d_in[4 + 2 * l];
    }

    char* ws = (char*)d_ws;
    size_t off = 0;
    auto alloc = [&](size_t bytes) -> void* {
        void* p = ws + off;
        off += (bytes + 255) / 256 * 256;
        return p;
    };
    int* flag = (int*)alloc(4);
    int* deg = (int*)alloc((size_t)N_NODES * 4);
    int* cursor = (int*)alloc((size_t)N_NODES * 4);
    size_t zbytes = off;  // zero [flag, deg, cursor] in one memset
    int* offs = (int*)alloc((size_t)(N_NODES + 1) * 4);
    int* bsum = (int*)alloc(256 * 4);
    int* csr_src = (int*)alloc((size_t)N_EDGES * 4);
    float* csr_w = (float*)alloc((size_t)N_EDGES * 4);
    float* dinv = (float*)alloc((size_t)N_NODES * 4);
    unsigned short* whi = (unsigned short*)alloc((size_t)4 * 16384 * 2);  // 4 layers W hi (frag layout)
    unsigned short* wlo = (unsigned short*)alloc((size_t)4 * 16384 * 2);
    float* B0 = (float*)alloc((size_t)N_NODES * 128 * 4);
    float* B1 = (float*)alloc((size_t)N_NODES * 128 * 4);
    // g6 / xw3 are never live while B1 holds data -> alias into B1 (ws trim)
    float* g6 = B1;
    float* xw3 = B1;

    hipMemsetAsync(d_ws, 0, zbytes, stream);

    k_detect<<<16, 256, 0, stream>>>(E, flag);
    k_count<<<(N_EDGES + 255) / 256, 256, 0, stream>>>(E, flag, deg);
    int nb = (N_NODES + 1023) / 1024;  // 98
    k_scan1<<<nb, 256, 0, stream>>>(deg, offs, bsum, dinv);
    k_scan2<<<1, 256, 0, stream>>>(bsum, nb);
    k_scan3<<<(N_NODES + 255) / 256, 256, 0, stream>>>(offs, bsum);
    k_fill<<<(N_EDGES + 255) / 256, 256, 0, stream>>>(E, flag, dinv, offs, cursor, csr_src, csr_w);
    k_wsplit<<<32, 256, 0, stream>>>(Wl[1], Wl[2], Wl[3], Wl[4], whi, wlo);

    // layer 0: aggregate (6-wide) then GEMM 6->128 + bias + relu
    k_agg6<<<(N_NODES + 255) / 256, 256, 0, stream>>>(x, sdf, dinv, offs, csr_src, csr_w, g6);
    k_gemm6<<<(N_NODES + 1) / 2, 256, 0, stream>>>(g6, Wl[0], bl[0], B0);

    // layers 1..4: MFMA GEMM 128->128 then aggregate + bias + relu
    const int GGRID = (N_NODES + 63) / 64;
    for (int l = 1; l <= 4; l++) {
        size_t lo = (size_t)(l - 1) * 16384;
        k_gemm128m<<<GGRID, 256, 0, stream>>>(B0, whi + lo, wlo + lo, B1);
        k_agg128<<<(N_NODES + 15) / 16, 256, 0, stream>>>(B1, bl[l], dinv, offs, csr_src, csr_w, B0);
    }

    // layer 5: GEMM 128->3 then aggregate + bias (no relu)
    k_gemm3<<<(N_NODES + 255) / 256, 256, 0, stream>>>(B0, Wl[5], xw3);
    k_agg3<<<(N_NODES + 255) / 256, 256, 0, stream>>>(xw3, bl[5], dinv, offs, csr_src, csr_w, (float*)d_out);
}

// Round 13
// 510.433 us; speedup vs baseline: 1.5241x; 1.1749x over previous
//
#include <hip/hip_runtime.h>

#define N_NODES 100000
#define N_EDGES 600000
#define IN_CH 5
#define HID 128

typedef __attribute__((ext_vector_type(8))) short short8v;   // 8 bf16 (4 VGPR)
typedef __attribute__((ext_vector_type(4))) float f32x4;     // MFMA acc

__device__ __forceinline__ unsigned short f2bf(float f) {    // fp32 -> bf16 RNE
    unsigned u = __float_as_uint(f);
    unsigned r = (u + 0x7fffu + ((u >> 16) & 1u)) >> 16;
    return (unsigned short)r;
}
__device__ __forceinline__ float bf2f(unsigned short h) { return __uint_as_float(((unsigned)h) << 16); }

// 8 bf16 packed in a uint4 -> fma into a[0..7] (lo ushort = even feature)
__device__ __forceinline__ void bf8_fma(const uint4 u, float w, float* a) {
    a[0] += w * __uint_as_float(u.x << 16);
    a[1] += w * __uint_as_float(u.x & 0xffff0000u);
    a[2] += w * __uint_as_float(u.y << 16);
    a[3] += w * __uint_as_float(u.y & 0xffff0000u);
    a[4] += w * __uint_as_float(u.z << 16);
    a[5] += w * __uint_as_float(u.z & 0xffff0000u);
    a[6] += w * __uint_as_float(u.w << 16);
    a[7] += w * __uint_as_float(u.w & 0xffff0000u);
}

// ---------------- edge dtype detection (int64 vs int32 layout) ----------------
__global__ __launch_bounds__(256) void k_detect(const unsigned* __restrict__ E, int* __restrict__ flag) {
    int t = blockIdx.x * blockDim.x + threadIdx.x;
    if (t < 4096) {
        if (E[2 * t + 1] != 0u) atomicOr(flag, 1);
    }
}

__device__ __forceinline__ int edge_elem(const unsigned* __restrict__ E, int elem, int is64) {
    return (int)E[is64 ? (2 * elem) : elem];
}

// ---------------- degree count ----------------
__global__ __launch_bounds__(256) void k_count(const unsigned* __restrict__ E, const int* __restrict__ flag,
                                               int* __restrict__ deg) {
    int e = blockIdx.x * blockDim.x + threadIdx.x;
    int is64 = (*flag == 0) ? 1 : 0;
    if (e < N_EDGES) {
        int d = edge_elem(E, N_EDGES + e, is64);
        atomicAdd(&deg[d], 1);
    }
}

// ---------------- exclusive scan (3-kernel), dinv fused into pass 1 ----------------
__global__ __launch_bounds__(256) void k_scan1(const int* __restrict__ deg, int* __restrict__ offs,
                                               int* __restrict__ bsum, float* __restrict__ dinv) {
    __shared__ int sd[256];
    int t = threadIdx.x;
    int base = blockIdx.x * 1024 + t * 4;
    int v0 = (base + 0 < N_NODES) ? deg[base + 0] : 0;
    int v1 = (base + 1 < N_NODES) ? deg[base + 1] : 0;
    int v2 = (base + 2 < N_NODES) ? deg[base + 2] : 0;
    int v3 = (base + 3 < N_NODES) ? deg[base + 3] : 0;
    if (base + 0 < N_NODES) dinv[base + 0] = rsqrtf((float)v0 + 1.0f);
    if (base + 1 < N_NODES) dinv[base + 1] = rsqrtf((float)v1 + 1.0f);
    if (base + 2 < N_NODES) dinv[base + 2] = rsqrtf((float)v2 + 1.0f);
    if (base + 3 < N_NODES) dinv[base + 3] = rsqrtf((float)v3 + 1.0f);
    sd[t] = v0 + v1 + v2 + v3;
    __syncthreads();
    for (int off = 1; off < 256; off <<= 1) {
        int x = sd[t];
        if (t >= off) x += sd[t - off];
        __syncthreads();
        sd[t] = x;
        __syncthreads();
    }
    int run = (t == 0) ? 0 : sd[t - 1];
    if (base + 0 < N_NODES) offs[base + 0] = run; run += v0;
    if (base + 1 < N_NODES) offs[base + 1] = run; run += v1;
    if (base + 2 < N_NODES) offs[base + 2] = run; run += v2;
    if (base + 3 < N_NODES) offs[base + 3] = run;
    if (t == 255) bsum[blockIdx.x] = sd[255];
}

__global__ __launch_bounds__(256) void k_scan2(int* __restrict__ bsum, int nb) {
    __shared__ int sd[256];
    int t = threadIdx.x;
    sd[t] = (t < nb) ? bsum[t] : 0;
    __syncthreads();
    for (int off = 1; off < 256; off <<= 1) {
        int x = sd[t];
        if (t >= off) x += sd[t - off];
        __syncthreads();
        sd[t] = x;
        __syncthreads();
    }
    if (t < nb) bsum[t] = (t == 0) ? 0 : sd[t - 1];
}

__global__ __launch_bounds__(256) void k_scan3(int* __restrict__ offs, const int* __restrict__ bsum) {
    int i = blockIdx.x * blockDim.x + threadIdx.x;
    if (i < N_NODES) offs[i] += bsum[i >> 10];
    if (i == 0) offs[N_NODES] = N_EDGES;
}

// ---------------- CSR fill ----------------
__global__ __launch_bounds__(256) void k_fill(const unsigned* __restrict__ E, const int* __restrict__ flag,
                                              const float* __restrict__ dinv, const int* __restrict__ offs,
                                              int* __restrict__ cursor, int* __restrict__ csr_src,
                                              float* __restrict__ csr_w) {
    int e = blockIdx.x * blockDim.x + threadIdx.x;
    int is64 = (*flag == 0) ? 1 : 0;
    if (e < N_EDGES) {
        int s = edge_elem(E, e, is64);
        int d = edge_elem(E, N_EDGES + e, is64);
        int p = atomicAdd(&cursor[d], 1);
        int idx = offs[d] + p;
        csr_src[idx] = s;
        csr_w[idx] = dinv[s] * dinv[d];
    }
}

// ---------------- W split: fp32 [128][128] -> bf16 hi/lo in MFMA-fragment layout ----------------
__global__ __launch_bounds__(256) void k_wsplit(const float* __restrict__ W1, const float* __restrict__ W2,
                                                const float* __restrict__ W3, const float* __restrict__ W4,
                                                unsigned short* __restrict__ whi, unsigned short* __restrict__ wlo) {
    int t = blockIdx.x * 256 + threadIdx.x;  // 8192 threads: (lay, c, ct, l)
    if (t >= 8192) return;
    int lay = t >> 11;
    int rem = t & 2047;
    int c = rem >> 9;
    int ct = (rem >> 6) & 7;
    int l = rem & 63;
    const float* W = (lay == 0) ? W1 : (lay == 1) ? W2 : (lay == 2) ? W3 : W4;
    int col = ct * 16 + (l & 15);
    int kbase = c * 32 + ((l >> 4) << 3);
    unsigned short hi[8], lo[8];
#pragma unroll
    for (int e = 0; e < 8; e++) {
        float v = W[(size_t)(kbase + e) * 128 + col];
        hi[e] = f2bf(v);
        lo[e] = f2bf(v - bf2f(hi[e]));
    }
    size_t o = (size_t)t * 8;
    union { unsigned short u[8]; short8v v; } ph, pl;
#pragma unroll
    for (int e = 0; e < 8; e++) { ph.u[e] = hi[e]; pl.u[e] = lo[e]; }
    *(short8v*)&whi[o] = ph.v;
    *(short8v*)&wlo[o] = pl.v;
}

// ---------------- layer 0: aggregate on 6-wide input ----------------
__global__ __launch_bounds__(256) void k_agg6(const float* __restrict__ x, const float* __restrict__ sdf,
                                              const float* __restrict__ dinv, const int* __restrict__ offs,
                                              const int* __restrict__ csr_src, const float* __restrict__ csr_w,
                                              float* __restrict__ g) {
    int i = blockIdx.x * blockDim.x + threadIdx.x;
    if (i >= N_NODES) return;
    float dn = dinv[i];
    float dn2 = dn * dn;
    float a[6];
#pragma unroll
    for (int f = 0; f < IN_CH; f++) a[f] = dn2 * x[i * IN_CH + f];
    a[5] = dn2 * sdf[i];
    int e0 = offs[i], e1 = offs[i + 1];
    for (int e = e0; e < e1; e++) {
        int s = csr_src[e];
        float w = csr_w[e];
#pragma unroll
        for (int f = 0; f < IN_CH; f++) a[f] += w * x[s * IN_CH + f];
        a[5] += w * sdf[s];
    }
#pragma unroll
    for (int f = 0; f < 6; f++) g[i * 6 + f] = a[f];
}

// ---------------- layer 0 GEMM: [N,6] @ [6,128] + b, relu ----------------
__global__ __launch_bounds__(256) void k_gemm6(const float* __restrict__ g, const float* __restrict__ W,
                                               const float* __restrict__ b, float* __restrict__ out) {
    __shared__ float Ws[6 * 128];
    __shared__ float bs[128];
    int t = threadIdx.x;
    for (int j = t; j < 768; j += 256) Ws[j] = W[j];
    if (t < 128) bs[t] = b[t];
    __syncthreads();
    int node = blockIdx.x * 2 + (t >> 7);
    int f = t & 127;
    if (node >= N_NODES) return;
    float acc = bs[f];
#pragma unroll
    for (int k = 0; k < 6; k++) acc += g[node * 6 + k] * Ws[k * 128 + f];
    out[node * 128 + f] = fmaxf(acc, 0.0f);
}

// ---------------- hidden GEMM via MFMA, 3-term split-bf16, OUTPUT bf16 ----------------
// No LDS, no barriers. Wave owns 16 rows x 128 cols. All A-loads hoisted.
// Output written as bf16 (packed 2/dword via shfl_xor pairing): halves write
// traffic and makes the 25.6 MB xw buffer cache-resident for the gather.
__global__ __launch_bounds__(256) void k_gemm128m(const float* __restrict__ H, const unsigned short* __restrict__ whi,
                                                  const unsigned short* __restrict__ wlo,
                                                  unsigned short* __restrict__ out) {
    int t = threadIdx.x;
    int wv = t >> 6;
    int l = t & 63;
    int row0 = blockIdx.x * 64 + wv * 16;
    int arow = row0 + (l & 15);
    if (arow >= N_NODES) arow = N_NODES - 1;  // clamp loads; stores guarded

    // ---- load entire A strip for this lane: 4 chunks x 8 floats ----
    const float4* ap = (const float4*)&H[(size_t)arow * 128 + ((l >> 4) << 3)];
    float4 araw[8];
#pragma unroll
    for (int c = 0; c < 4; c++) {
        araw[2 * c] = ap[c * 8];
        araw[2 * c + 1] = ap[c * 8 + 1];
    }
    union { unsigned short u[8]; short8v v; } ah[4], al[4];
#pragma unroll
    for (int c = 0; c < 4; c++) {
        float av[8] = {araw[2 * c].x, araw[2 * c].y, araw[2 * c].z, araw[2 * c].w,
                       araw[2 * c + 1].x, araw[2 * c + 1].y, araw[2 * c + 1].z, araw[2 * c + 1].w};
#pragma unroll
        for (int e = 0; e < 8; e++) {
            unsigned short h = f2bf(av[e]);
            ah[c].u[e] = h;
            al[c].u[e] = f2bf(av[e] - bf2f(h));
        }
    }

    f32x4 acc[8];
#pragma unroll
    for (int ct = 0; ct < 8; ct++) acc[ct] = (f32x4){0.f, 0.f, 0.f, 0.f};

#pragma unroll
    for (int c = 0; c < 4; c++) {
        const short8v* bh = (const short8v*)&whi[((size_t)(c * 8) * 64 + l) * 8];
        const short8v* bl = (const short8v*)&wlo[((size_t)(c * 8) * 64 + l) * 8];
#pragma unroll
        for (int ct = 0; ct < 8; ct++) {
            short8v vbh = bh[ct * 64];
            short8v vbl = bl[ct * 64];
            acc[ct] = __builtin_amdgcn_mfma_f32_16x16x32_bf16(ah[c].v, vbh, acc[ct], 0, 0, 0);
            acc[ct] = __builtin_amdgcn_mfma_f32_16x16x32_bf16(al[c].v, vbh, acc[ct], 0, 0, 0);
            acc[ct] = __builtin_amdgcn_mfma_f32_16x16x32_bf16(ah[c].v, vbl, acc[ct], 0, 0, 0);
        }
    }

    // C/D layout: col = lane&15, row = (lane>>4)*4 + reg.
    // Pack col pairs (even,odd) via shfl_xor(1); even lane writes one dword.
    int rbase = row0 + ((l >> 4) << 2);
    int col = l & 15;
#pragma unroll
    for (int ct = 0; ct < 8; ct++) {
#pragma unroll
        for (int r = 0; r < 4; r++) {
            float mine = acc[ct][r];
            float other = __shfl_xor(mine, 1, 64);
            int row = rbase + r;
            if (!(l & 1) && row < N_NODES) {
                unsigned packed = (unsigned)f2bf(mine) | ((unsigned)f2bf(other) << 16);
                *(unsigned*)&out[(size_t)row * 128 + ct * 16 + col] = packed;
            }
        }
    }
}

// ---------------- hidden aggregation from bf16 xw: 16-lane group per node ----------------
// One 16B load per edge per lane (8 bf16), fp32 accumulate, 4-edge unroll.
// Output (h) stays fp32. Non-temporal stores.
__global__ __launch_bounds__(256) void k_agg128(const unsigned short* __restrict__ xwb,
                                                const float* __restrict__ bias,
                                                const float* __restrict__ dinv, const int* __restrict__ offs,
                                                const int* __restrict__ csr_src, const float* __restrict__ csr_w,
                                                float* __restrict__ out) {
    int t = threadIdx.x;
    int grp = t >> 4;   // 0..15
    int sub = t & 15;   // features sub*8 .. sub*8+7
    int node = blockIdx.x * 16 + grp;
    if (node >= N_NODES) return;
    const uint4* xb = (const uint4*)xwb;  // row = 16 uint4 (128 bf16)
    float dn = dinv[node];
    float dn2 = dn * dn;
    float accA[8], accB[8], accC[8], accD[8];
#pragma unroll
    for (int f = 0; f < 8; f++) { accA[f] = 0.f; accB[f] = 0.f; accC[f] = 0.f; accD[f] = 0.f; }
    uint4 sv = xb[(size_t)node * 16 + sub];
    bf8_fma(sv, dn2, accA);
    int e0 = offs[node], e1 = offs[node + 1];
    int e = e0;
    for (; e + 3 < e1; e += 4) {
        int s0 = csr_src[e], s1 = csr_src[e + 1], s2 = csr_src[e + 2], s3 = csr_src[e + 3];
        float w0 = csr_w[e], w1 = csr_w[e + 1], w2 = csr_w[e + 2], w3 = csr_w[e + 3];
        uint4 u0 = xb[(size_t)s0 * 16 + sub];
        uint4 u1 = xb[(size_t)s1 * 16 + sub];
        uint4 u2 = xb[(size_t)s2 * 16 + sub];
        uint4 u3 = xb[(size_t)s3 * 16 + sub];
        bf8_fma(u0, w0, accA);
        bf8_fma(u1, w1, accB);
        bf8_fma(u2, w2, accC);
        bf8_fma(u3, w3, accD);
    }
    for (; e < e1; e++) {
        int s0 = csr_src[e];
        float w0 = csr_w[e];
        uint4 u0 = xb[(size_t)s0 * 16 + sub];
        bf8_fma(u0, w0, accA);
    }
    float4 b0 = ((const float4*)bias)[sub * 2];
    float4 b1 = ((const float4*)bias)[sub * 2 + 1];
    f32x4 o0, o1;
    o0[0] = fmaxf(accA[0] + accB[0] + accC[0] + accD[0] + b0.x, 0.0f);
    o0[1] = fmaxf(accA[1] + accB[1] + accC[1] + accD[1] + b0.y, 0.0f);
    o0[2] = fmaxf(accA[2] + accB[2] + accC[2] + accD[2] + b0.z, 0.0f);
    o0[3] = fmaxf(accA[3] + accB[3] + accC[3] + accD[3] + b0.w, 0.0f);
    o1[0] = fmaxf(accA[4] + accB[4] + accC[4] + accD[4] + b1.x, 0.0f);
    o1[1] = fmaxf(accA[5] + accB[5] + accC[5] + accD[5] + b1.y, 0.0f);
    o1[2] = fmaxf(accA[6] + accB[6] + accC[6] + accD[6] + b1.z, 0.0f);
    o1[3] = fmaxf(accA[7] + accB[7] + accC[7] + accD[7] + b1.w, 0.0f);
    f32x4* o = (f32x4*)out;
    size_t self = (size_t)node * 32 + sub * 2;
    __builtin_nontemporal_store(o0, &o[self]);
    __builtin_nontemporal_store(o1, &o[self + 1]);
}

// ---------------- final GEMM: [N,128] @ [128,3] ----------------
__global__ __launch_bounds__(256) void k_gemm3(const float* __restrict__ H, const float* __restrict__ W,
                                               float* __restrict__ out) {
    __shared__ float Ws[128 * 3];
    int t = threadIdx.x;
    for (int j = t; j < 384; j += 256) Ws[j] = W[j];
    __syncthreads();
    int i = blockIdx.x * 256 + t;
    if (i >= N_NODES) return;
    float a0 = 0.f, a1 = 0.f, a2 = 0.f;
#pragma unroll
    for (int k = 0; k < 128; k += 4) {
        float4 v = *(const float4*)&H[(size_t)i * 128 + k];
        a0 += v.x * Ws[(k + 0) * 3 + 0] + v.y * Ws[(k + 1) * 3 + 0] + v.z * Ws[(k + 2) * 3 + 0] + v.w * Ws[(k + 3) * 3 + 0];
        a1 += v.x * Ws[(k + 0) * 3 + 1] + v.y * Ws[(k + 1) * 3 + 1] + v.z * Ws[(k + 2) * 3 + 1] + v.w * Ws[(k + 3) * 3 + 1];
        a2 += v.x * Ws[(k + 0) * 3 + 2] + v.y * Ws[(k + 1) * 3 + 2] + v.z * Ws[(k + 2) * 3 + 2] + v.w * Ws[(k + 3) * 3 + 2];
    }
    out[(size_t)i * 3 + 0] = a0;
    out[(size_t)i * 3 + 1] = a1;
    out[(size_t)i * 3 + 2] = a2;
}

// ---------------- final aggregation on 3 feats + bias (no relu) ----------------
__global__ __launch_bounds__(256) void k_agg3(const float* __restrict__ xw3, const float* __restrict__ b,
                                              const float* __restrict__ dinv, const int* __restrict__ offs,
                                              const int* __restrict__ csr_src, const float* __restrict__ csr_w,
                                              float* __restrict__ out) {
    int i = blockIdx.x * blockDim.x + threadIdx.x;
    if (i >= N_NODES) return;
    float dn = dinv[i];
    float dn2 = dn * dn;
    float a0 = dn2 * xw3[(size_t)i * 3 + 0];
    float a1 = dn2 * xw3[(size_t)i * 3 + 1];
    float a2 = dn2 * xw3[(size_t)i * 3 + 2];
    int e0 = offs[i], e1 = offs[i + 1];
    for (int e = e0; e < e1; e++) {
        int s = csr_src[e];
        float w = csr_w[e];
        a0 += w * xw3[(size_t)s * 3 + 0];
        a1 += w * xw3[(size_t)s * 3 + 1];
        a2 += w * xw3[(size_t)s * 3 + 2];
    }
    out[(size_t)i * 3 + 0] = a0 + b[0];
    out[(size_t)i * 3 + 1] = a1 + b[1];
    out[(size_t)i * 3 + 2] = a2 + b[2];
}

extern "C" void kernel_launch(void* const* d_in, const int* in_sizes, int n_in,
                              void* d_out, int out_size, void* d_ws, size_t ws_size,
                              hipStream_t stream) {
    const float* x = (const float*)d_in[0];
    const float* sdf = (const float*)d_in[1];
    const unsigned* E = (const unsigned*)d_in[2];
    const float* Wl[6];
    const float* bl[6];
    for (int l = 0; l < 6; l++) {
        Wl[l] = (const float*)d_in[3 + 2 * l];
        bl[l] = (const float*)d_in[4 + 2 * l];
    }

    char* ws = (char*)d_ws;
    size_t off = 0;
    auto alloc = [&](size_t bytes) -> void* {
        void* p = ws + off;
        off += (bytes + 255) / 256 * 256;
        return p;
    };
    int* flag = (int*)alloc(4);
    int* deg = (int*)alloc((size_t)N_NODES * 4);
    int* cursor = (int*)alloc((size_t)N_NODES * 4);
    size_t zbytes = off;  // zero [flag, deg, cursor] in one memset
    int* offs = (int*)alloc((size_t)(N_NODES + 1) * 4);
    int* bsum = (int*)alloc(256 * 4);
    int* csr_src = (int*)alloc((size_t)N_EDGES * 4);
    float* csr_w = (float*)alloc((size_t)N_EDGES * 4);
    float* dinv = (float*)alloc((size_t)N_NODES * 4);
    unsigned short* whi = (unsigned short*)alloc((size_t)4 * 16384 * 2);  // 4 layers W hi (frag layout)
    unsigned short* wlo = (unsigned short*)alloc((size_t)4 * 16384 * 2);
    float* B0 = (float*)alloc((size_t)N_NODES * 128 * 4);                 // fp32 h
    unsigned short* B1 = (unsigned short*)alloc((size_t)N_NODES * 128 * 2);  // bf16 xw
    // g6 / xw3 are never live while B1 holds data -> alias into B1 (ws trim)
    float* g6 = (float*)B1;
    float* xw3 = (float*)B1;

    hipMemsetAsync(d_ws, 0, zbytes, stream);

    k_detect<<<16, 256, 0, stream>>>(E, flag);
    k_count<<<(N_EDGES + 255) / 256, 256, 0, stream>>>(E, flag, deg);
    int nb = (N_NODES + 1023) / 1024;  // 98
    k_scan1<<<nb, 256, 0, stream>>>(deg, offs, bsum, dinv);
    k_scan2<<<1, 256, 0, stream>>>(bsum, nb);
    k_scan3<<<(N_NODES + 255) / 256, 256, 0, stream>>>(offs, bsum);
    k_fill<<<(N_EDGES + 255) / 256, 256, 0, stream>>>(E, flag, dinv, offs, cursor, csr_src, csr_w);
    k_wsplit<<<32, 256, 0, stream>>>(Wl[1], Wl[2], Wl[3], Wl[4], whi, wlo);

    // layer 0: aggregate (6-wide) then GEMM 6->128 + bias + relu
    k_agg6<<<(N_NODES + 255) / 256, 256, 0, stream>>>(x, sdf, dinv, offs, csr_src, csr_w, g6);
    k_gemm6<<<(N_NODES + 1) / 2, 256, 0, stream>>>(g6, Wl[0], bl[0], B0);

    // layers 1..4: MFMA GEMM 128->128 (bf16 out) then aggregate + bias + relu (fp32 out)
    const int GGRID = (N_NODES + 63) / 64;
    for (int l = 1; l <= 4; l++) {
        size_t lo = (size_t)(l - 1) * 16384;
        k_gemm128m<<<GGRID, 256, 0, stream>>>(B0, whi + lo, wlo + lo, B1);
        k_agg128<<<(N_NODES + 15) / 16, 256, 0, stream>>>(B1, bl[l], dinv, offs, csr_src, csr_w, B0);
    }

    // layer 5: GEMM 128->3 then aggregate + bias (no relu)
    k_gemm3<<<(N_NODES + 255) / 256, 256, 0, stream>>>(B0, Wl[5], xw3);
    k_agg3<<<(N_NODES + 255) / 256, 256, 0, stream>>>(xw3, bl[5], dinv, offs, csr_src, csr_w, (float*)d_out);
}

// Round 15
// 482.419 us; speedup vs baseline: 1.6126x; 1.0581x over previous
//
#include <hip/hip_runtime.h>

#define N_NODES 100000
#define N_EDGES 600000
#define IN_CH 5
#define HID 128

typedef __attribute__((ext_vector_type(8))) short short8v;   // 8 bf16 (4 VGPR)
typedef __attribute__((ext_vector_type(4))) float f32x4;     // MFMA acc

__device__ __forceinline__ unsigned short f2bf(float f) {    // fp32 -> bf16 RNE
    unsigned u = __float_as_uint(f);
    unsigned r = (u + 0x7fffu + ((u >> 16) & 1u)) >> 16;
    return (unsigned short)r;
}
__device__ __forceinline__ float bf2f(unsigned short h) { return __uint_as_float(((unsigned)h) << 16); }

// 8 bf16 packed in a uint4 -> fma into a[0..7] (lo ushort = even feature)
__device__ __forceinline__ void bf8_fma(const uint4 u, float w, float* a) {
    a[0] += w * __uint_as_float(u.x << 16);
    a[1] += w * __uint_as_float(u.x & 0xffff0000u);
    a[2] += w * __uint_as_float(u.y << 16);
    a[3] += w * __uint_as_float(u.y & 0xffff0000u);
    a[4] += w * __uint_as_float(u.z << 16);
    a[5] += w * __uint_as_float(u.z & 0xffff0000u);
    a[6] += w * __uint_as_float(u.w << 16);
    a[7] += w * __uint_as_float(u.w & 0xffff0000u);
}

// ---------------- edge dtype detection (int64 vs int32 layout) ----------------
__global__ __launch_bounds__(256) void k_detect(const unsigned* __restrict__ E, int* __restrict__ flag) {
    int t = blockIdx.x * blockDim.x + threadIdx.x;
    if (t < 4096) {
        if (E[2 * t + 1] != 0u) atomicOr(flag, 1);
    }
}

__device__ __forceinline__ int edge_elem(const unsigned* __restrict__ E, int elem, int is64) {
    return (int)E[is64 ? (2 * elem) : elem];
}

// ---------------- degree count ----------------
__global__ __launch_bounds__(256) void k_count(const unsigned* __restrict__ E, const int* __restrict__ flag,
                                               int* __restrict__ deg) {
    int e = blockIdx.x * blockDim.x + threadIdx.x;
    int is64 = (*flag == 0) ? 1 : 0;
    if (e < N_EDGES) {
        int d = edge_elem(E, N_EDGES + e, is64);
        atomicAdd(&deg[d], 1);
    }
}

// ---------------- exclusive scan (3-kernel), dinv fused into pass 1 ----------------
__global__ __launch_bounds__(256) void k_scan1(const int* __restrict__ deg, int* __restrict__ offs,
                                               int* __restrict__ bsum, float* __restrict__ dinv) {
    __shared__ int sd[256];
    int t = threadIdx.x;
    int base = blockIdx.x * 1024 + t * 4;
    int v0 = (base + 0 < N_NODES) ? deg[base + 0] : 0;
    int v1 = (base + 1 < N_NODES) ? deg[base + 1] : 0;
    int v2 = (base + 2 < N_NODES) ? deg[base + 2] : 0;
    int v3 = (base + 3 < N_NODES) ? deg[base + 3] : 0;
    if (base + 0 < N_NODES) dinv[base + 0] = rsqrtf((float)v0 + 1.0f);
    if (base + 1 < N_NODES) dinv[base + 1] = rsqrtf((float)v1 + 1.0f);
    if (base + 2 < N_NODES) dinv[base + 2] = rsqrtf((float)v2 + 1.0f);
    if (base + 3 < N_NODES) dinv[base + 3] = rsqrtf((float)v3 + 1.0f);
    sd[t] = v0 + v1 + v2 + v3;
    __syncthreads();
    for (int off = 1; off < 256; off <<= 1) {
        int x = sd[t];
        if (t >= off) x += sd[t - off];
        __syncthreads();
        sd[t] = x;
        __syncthreads();
    }
    int run = (t == 0) ? 0 : sd[t - 1];
    if (base + 0 < N_NODES) offs[base + 0] = run; run += v0;
    if (base + 1 < N_NODES) offs[base + 1] = run; run += v1;
    if (base + 2 < N_NODES) offs[base + 2] = run; run += v2;
    if (base + 3 < N_NODES) offs[base + 3] = run;
    if (t == 255) bsum[blockIdx.x] = sd[255];
}

__global__ __launch_bounds__(256) void k_scan2(int* __restrict__ bsum, int nb) {
    __shared__ int sd[256];
    int t = threadIdx.x;
    sd[t] = (t < nb) ? bsum[t] : 0;
    __syncthreads();
    for (int off = 1; off < 256; off <<= 1) {
        int x = sd[t];
        if (t >= off) x += sd[t - off];
        __syncthreads();
        sd[t] = x;
        __syncthreads();
    }
    if (t < nb) bsum[t] = (t == 0) ? 0 : sd[t - 1];
}

__global__ __launch_bounds__(256) void k_scan3(int* __restrict__ offs, const int* __restrict__ bsum) {
    int i = blockIdx.x * blockDim.x + threadIdx.x;
    if (i < N_NODES) offs[i] += bsum[i >> 10];
    if (i == 0) offs[N_NODES] = N_EDGES;
}

// ---------------- CSR fill ----------------
__global__ __launch_bounds__(256) void k_fill(const unsigned* __restrict__ E, const int* __restrict__ flag,
                                              const float* __restrict__ dinv, const int* __restrict__ offs,
                                              int* __restrict__ cursor, int* __restrict__ csr_src,
                                              float* __restrict__ csr_w) {
    int e = blockIdx.x * blockDim.x + threadIdx.x;
    int is64 = (*flag == 0) ? 1 : 0;
    if (e < N_EDGES) {
        int s = edge_elem(E, e, is64);
        int d = edge_elem(E, N_EDGES + e, is64);
        int p = atomicAdd(&cursor[d], 1);
        int idx = offs[d] + p;
        csr_src[idx] = s;
        csr_w[idx] = dinv[s] * dinv[d];
    }
}

// ---------------- W split: fp32 [128][128] -> bf16 hi/lo in MFMA-fragment layout ----------------
__global__ __launch_bounds__(256) void k_wsplit(const float* __restrict__ W1, const float* __restrict__ W2,
                                                const float* __restrict__ W3, const float* __restrict__ W4,
                                                unsigned short* __restrict__ whi, unsigned short* __restrict__ wlo) {
    int t = blockIdx.x * 256 + threadIdx.x;  // 8192 threads: (lay, c, ct, l)
    if (t >= 8192) return;
    int lay = t >> 11;
    int rem = t & 2047;
    int c = rem >> 9;
    int ct = (rem >> 6) & 7;
    int l = rem & 63;
    const float* W = (lay == 0) ? W1 : (lay == 1) ? W2 : (lay == 2) ? W3 : W4;
    int col = ct * 16 + (l & 15);
    int kbase = c * 32 + ((l >> 4) << 3);
    unsigned short hi[8], lo[8];
#pragma unroll
    for (int e = 0; e < 8; e++) {
        float v = W[(size_t)(kbase + e) * 128 + col];
        hi[e] = f2bf(v);
        lo[e] = f2bf(v - bf2f(hi[e]));
    }
    size_t o = (size_t)t * 8;
    union { unsigned short u[8]; short8v v; } ph, pl;
#pragma unroll
    for (int e = 0; e < 8; e++) { ph.u[e] = hi[e]; pl.u[e] = lo[e]; }
    *(short8v*)&whi[o] = ph.v;
    *(short8v*)&wlo[o] = pl.v;
}

// ---------------- layer 0: aggregate on 6-wide input ----------------
__global__ __launch_bounds__(256) void k_agg6(const float* __restrict__ x, const float* __restrict__ sdf,
                                              const float* __restrict__ dinv, const int* __restrict__ offs,
                                              const int* __restrict__ csr_src, const float* __restrict__ csr_w,
                                              float* __restrict__ g) {
    int i = blockIdx.x * blockDim.x + threadIdx.x;
    if (i >= N_NODES) return;
    float dn = dinv[i];
    float dn2 = dn * dn;
    float a[6];
#pragma unroll
    for (int f = 0; f < IN_CH; f++) a[f] = dn2 * x[i * IN_CH + f];
    a[5] = dn2 * sdf[i];
    int e0 = offs[i], e1 = offs[i + 1];
    for (int e = e0; e < e1; e++) {
        int s = csr_src[e];
        float w = csr_w[e];
#pragma unroll
        for (int f = 0; f < IN_CH; f++) a[f] += w * x[s * IN_CH + f];
        a[5] += w * sdf[s];
    }
#pragma unroll
    for (int f = 0; f < 6; f++) g[i * 6 + f] = a[f];
}

// ---------------- layer 0 GEMM: [N,6] @ [6,128] + b, relu; float4 stores ----------------
// 8 nodes/block, 32 threads/node, 4 features/thread -> 16B/lane coalesced
// writes (fix for 1.24 TB/s scalar-store bottleneck, R13 counters).
__global__ __launch_bounds__(256) void k_gemm6(const float* __restrict__ g, const float* __restrict__ W,
                                               const float* __restrict__ b, float* __restrict__ out) {
    __shared__ float Ws[6 * 128];
    __shared__ float bs[128];
    int t = threadIdx.x;
    for (int j = t; j < 768; j += 256) Ws[j] = W[j];
    if (t < 128) bs[t] = b[t];
    __syncthreads();
    int node = blockIdx.x * 8 + (t >> 5);
    int f0 = (t & 31) * 4;
    if (node >= N_NODES) return;
    float gk[6];
#pragma unroll
    for (int k = 0; k < 6; k++) gk[k] = g[node * 6 + k];  // broadcast within node's 32 threads
    float4 acc = *(const float4*)&bs[f0];
#pragma unroll
    for (int k = 0; k < 6; k++) {
        float4 wv = *(const float4*)&Ws[k * 128 + f0];
        acc.x += gk[k] * wv.x;
        acc.y += gk[k] * wv.y;
        acc.z += gk[k] * wv.z;
        acc.w += gk[k] * wv.w;
    }
    acc.x = fmaxf(acc.x, 0.0f);
    acc.y = fmaxf(acc.y, 0.0f);
    acc.z = fmaxf(acc.z, 0.0f);
    acc.w = fmaxf(acc.w, 0.0f);
    *(float4*)&out[(size_t)node * 128 + f0] = acc;
}

// ---------------- hidden GEMM via MFMA, 3-term split-bf16, OUTPUT bf16 ----------------
// No LDS, no barriers. Wave owns 16 rows x 128 cols. All A-loads hoisted.
// Output written as bf16 (packed 2/dword via shfl_xor pairing): halves write
// traffic and makes the 25.6 MB xw buffer cache-resident for the gather.
__global__ __launch_bounds__(256) void k_gemm128m(const float* __restrict__ H, const unsigned short* __restrict__ whi,
                                                  const unsigned short* __restrict__ wlo,
                                                  unsigned short* __restrict__ out) {
    int t = threadIdx.x;
    int wv = t >> 6;
    int l = t & 63;
    int row0 = blockIdx.x * 64 + wv * 16;
    int arow = row0 + (l & 15);
    if (arow >= N_NODES) arow = N_NODES - 1;  // clamp loads; stores guarded

    // ---- load entire A strip for this lane: 4 chunks x 8 floats ----
    const float4* ap = (const float4*)&H[(size_t)arow * 128 + ((l >> 4) << 3)];
    float4 araw[8];
#pragma unroll
    for (int c = 0; c < 4; c++) {
        araw[2 * c] = ap[c * 8];
        araw[2 * c + 1] = ap[c * 8 + 1];
    }
    union { unsigned short u[8]; short8v v; } ah[4], al[4];
#pragma unroll
    for (int c = 0; c < 4; c++) {
        float av[8] = {araw[2 * c].x, araw[2 * c].y, araw[2 * c].z, araw[2 * c].w,
                       araw[2 * c + 1].x, araw[2 * c + 1].y, araw[2 * c + 1].z, araw[2 * c + 1].w};
#pragma unroll
        for (int e = 0; e < 8; e++) {
            unsigned short h = f2bf(av[e]);
            ah[c].u[e] = h;
            al[c].u[e] = f2bf(av[e] - bf2f(h));
        }
    }

    f32x4 acc[8];
#pragma unroll
    for (int ct = 0; ct < 8; ct++) acc[ct] = (f32x4){0.f, 0.f, 0.f, 0.f};

#pragma unroll
    for (int c = 0; c < 4; c++) {
        const short8v* bh = (const short8v*)&whi[((size_t)(c * 8) * 64 + l) * 8];
        const short8v* bl = (const short8v*)&wlo[((size_t)(c * 8) * 64 + l) * 8];
#pragma unroll
        for (int ct = 0; ct < 8; ct++) {
            short8v vbh = bh[ct * 64];
            short8v vbl = bl[ct * 64];
            acc[ct] = __builtin_amdgcn_mfma_f32_16x16x32_bf16(ah[c].v, vbh, acc[ct], 0, 0, 0);
            acc[ct] = __builtin_amdgcn_mfma_f32_16x16x32_bf16(al[c].v, vbh, acc[ct], 0, 0, 0);
            acc[ct] = __builtin_amdgcn_mfma_f32_16x16x32_bf16(ah[c].v, vbl, acc[ct], 0, 0, 0);
        }
    }

    // C/D layout: col = lane&15, row = (lane>>4)*4 + reg.
    // Pack col pairs (even,odd) via shfl_xor(1); even lane writes one dword.
    int rbase = row0 + ((l >> 4) << 2);
    int col = l & 15;
#pragma unroll
    for (int ct = 0; ct < 8; ct++) {
#pragma unroll
        for (int r = 0; r < 4; r++) {
            float mine = acc[ct][r];
            float other = __shfl_xor(mine, 1, 64);
            int row = rbase + r;
            if (!(l & 1) && row < N_NODES) {
                unsigned packed = (unsigned)f2bf(mine) | ((unsigned)f2bf(other) << 16);
                *(unsigned*)&out[(size_t)row * 128 + ct * 16 + col] = packed;
            }
        }
    }
}

// ---------------- hidden aggregation from bf16 xw: 16-lane group per node ----------------
// One 16B load per edge per lane (8 bf16), fp32 accumulate, 4-edge unroll.
// Output (h) stays fp32. Non-temporal stores.
__global__ __launch_bounds__(256) void k_agg128(const unsigned short* __restrict__ xwb,
                                                const float* __restrict__ bias,
                                                const float* __restrict__ dinv, const int* __restrict__ offs,
                                                const int* __restrict__ csr_src, const float* __restrict__ csr_w,
                                                float* __restrict__ out) {
    int t = threadIdx.x;
    int grp = t >> 4;   // 0..15
    int sub = t & 15;   // features sub*8 .. sub*8+7
    int node = blockIdx.x * 16 + grp;
    if (node >= N_NODES) return;
    const uint4* xb = (const uint4*)xwb;  // row = 16 uint4 (128 bf16)
    float dn = dinv[node];
    float dn2 = dn * dn;
    float accA[8], accB[8], accC[8], accD[8];
#pragma unroll
    for (int f = 0; f < 8; f++) { accA[f] = 0.f; accB[f] = 0.f; accC[f] = 0.f; accD[f] = 0.f; }
    uint4 sv = xb[(size_t)node * 16 + sub];
    bf8_fma(sv, dn2, accA);
    int e0 = offs[node], e1 = offs[node + 1];
    int e = e0;
    for (; e + 3 < e1; e += 4) {
        int s0 = csr_src[e], s1 = csr_src[e + 1], s2 = csr_src[e + 2], s3 = csr_src[e + 3];
        float w0 = csr_w[e], w1 = csr_w[e + 1], w2 = csr_w[e + 2], w3 = csr_w[e + 3];
        uint4 u0 = xb[(size_t)s0 * 16 + sub];
        uint4 u1 = xb[(size_t)s1 * 16 + sub];
        uint4 u2 = xb[(size_t)s2 * 16 + sub];
        uint4 u3 = xb[(size_t)s3 * 16 + sub];
        bf8_fma(u0, w0, accA);
        bf8_fma(u1, w1, accB);
        bf8_fma(u2, w2, accC);
        bf8_fma(u3, w3, accD);
    }
    for (; e < e1; e++) {
        int s0 = csr_src[e];
        float w0 = csr_w[e];
        uint4 u0 = xb[(size_t)s0 * 16 + sub];
        bf8_fma(u0, w0, accA);
    }
    float4 b0 = ((const float4*)bias)[sub * 2];
    float4 b1 = ((const float4*)bias)[sub * 2 + 1];
    f32x4 o0, o1;
    o0[0] = fmaxf(accA[0] + accB[0] + accC[0] + accD[0] + b0.x, 0.0f);
    o0[1] = fmaxf(accA[1] + accB[1] + accC[1] + accD[1] + b0.y, 0.0f);
    o0[2] = fmaxf(accA[2] + accB[2] + accC[2] + accD[2] + b0.z, 0.0f);
    o0[3] = fmaxf(accA[3] + accB[3] + accC[3] + accD[3] + b0.w, 0.0f);
    o1[0] = fmaxf(accA[4] + accB[4] + accC[4] + accD[4] + b1.x, 0.0f);
    o1[1] = fmaxf(accA[5] + accB[5] + accC[5] + accD[5] + b1.y, 0.0f);
    o1[2] = fmaxf(accA[6] + accB[6] + accC[6] + accD[6] + b1.z, 0.0f);
    o1[3] = fmaxf(accA[7] + accB[7] + accC[7] + accD[7] + b1.w, 0.0f);
    f32x4* o = (f32x4*)out;
    size_t self = (size_t)node * 32 + sub * 2;
    __builtin_nontemporal_store(o0, &o[self]);
    __builtin_nontemporal_store(o1, &o[self + 1]);
}

// ---------------- final GEMM: [N,128] @ [128,3] ----------------
__global__ __launch_bounds__(256) void k_gemm3(const float* __restrict__ H, const float* __restrict__ W,
                                               float* __restrict__ out) {
    __shared__ float Ws[128 * 3];
    int t = threadIdx.x;
    for (int j = t; j < 384; j += 256) Ws[j] = W[j];
    __syncthreads();
    int i = blockIdx.x * 256 + t;
    if (i >= N_NODES) return;
    float a0 = 0.f, a1 = 0.f, a2 = 0.f;
#pragma unroll
    for (int k = 0; k < 128; k += 4) {
        float4 v = *(const float4*)&H[(size_t)i * 128 + k];
        a0 += v.x * Ws[(k + 0) * 3 + 0] + v.y * Ws[(k + 1) * 3 + 0] + v.z * Ws[(k + 2) * 3 + 0] + v.w * Ws[(k + 3) * 3 + 0];
        a1 += v.x * Ws[(k + 0) * 3 + 1] + v.y * Ws[(k + 1) * 3 + 1] + v.z * Ws[(k + 2) * 3 + 1] + v.w * Ws[(k + 3) * 3 + 1];
        a2 += v.x * Ws[(k + 0) * 3 + 2] + v.y * Ws[(k + 1) * 3 + 2] + v.z * Ws[(k + 2) * 3 + 2] + v.w * Ws[(k + 3) * 3 + 2];
    }
    out[(size_t)i * 3 + 0] = a0;
    out[(size_t)i * 3 + 1] = a1;
    out[(size_t)i * 3 + 2] = a2;
}

// ---------------- final aggregation on 3 feats + bias (no relu) ----------------
__global__ __launch_bounds__(256) void k_agg3(const float* __restrict__ xw3, const float* __restrict__ b,
                                              const float* __restrict__ dinv, const int* __restrict__ offs,
                                              const int* __restrict__ csr_src, const float* __restrict__ csr_w,
                                              float* __restrict__ out) {
    int i = blockIdx.x * blockDim.x + threadIdx.x;
    if (i >= N_NODES) return;
    float dn = dinv[i];
    float dn2 = dn * dn;
    float a0 = dn2 * xw3[(size_t)i * 3 + 0];
    float a1 = dn2 * xw3[(size_t)i * 3 + 1];
    float a2 = dn2 * xw3[(size_t)i * 3 + 2];
    int e0 = offs[i], e1 = offs[i + 1];
    for (int e = e0; e < e1; e++) {
        int s = csr_src[e];
        float w = csr_w[e];
        a0 += w * xw3[(size_t)s * 3 + 0];
        a1 += w * xw3[(size_t)s * 3 + 1];
        a2 += w * xw3[(size_t)s * 3 + 2];
    }
    out[(size_t)i * 3 + 0] = a0 + b[0];
    out[(size_t)i * 3 + 1] = a1 + b[1];
    out[(size_t)i * 3 + 2] = a2 + b[2];
}

extern "C" void kernel_launch(void* const* d_in, const int* in_sizes, int n_in,
                              void* d_out, int out_size, void* d_ws, size_t ws_size,
                              hipStream_t stream) {
    const float* x = (const float*)d_in[0];
    const float* sdf = (const float*)d_in[1];
    const unsigned* E = (const unsigned*)d_in[2];
    const float* Wl[6];
    const float* bl[6];
    for (int l = 0; l < 6; l++) {
        Wl[l] = (const float*)d_in[3 + 2 * l];
        bl[l] = (const float*)d_in[4 + 2 * l];
    }

    char* ws = (char*)d_ws;
    size_t off = 0;
    auto alloc = [&](size_t bytes) -> void* {
        void* p = ws + off;
        off += (bytes + 255) / 256 * 256;
        return p;
    };
    int* flag = (int*)alloc(4);
    int* deg = (int*)alloc((size_t)N_NODES * 4);
    int* cursor = (int*)alloc((size_t)N_NODES * 4);
    size_t zbytes = off;  // zero [flag, deg, cursor] in one memset
    int* offs = (int*)alloc((size_t)(N_NODES + 1) * 4);
    int* bsum = (int*)alloc(256 * 4);
    int* csr_src = (int*)alloc((size_t)N_EDGES * 4);
    float* csr_w = (float*)alloc((size_t)N_EDGES * 4);
    float* dinv = (float*)alloc((size_t)N_NODES * 4);
    unsigned short* whi = (unsigned short*)alloc((size_t)4 * 16384 * 2);  // 4 layers W hi (frag layout)
    unsigned short* wlo = (unsigned short*)alloc((size_t)4 * 16384 * 2);
    float* B0 = (float*)alloc((size_t)N_NODES * 128 * 4);                 // fp32 h
    unsigned short* B1 = (unsigned short*)alloc((size_t)N_NODES * 128 * 2);  // bf16 xw
    // g6 / xw3 are never live while B1 holds data -> alias into B1 (ws trim)
    float* g6 = (float*)B1;
    float* xw3 = (float*)B1;

    hipMemsetAsync(d_ws, 0, zbytes, stream);

    k_detect<<<16, 256, 0, stream>>>(E, flag);
    k_count<<<(N_EDGES + 255) / 256, 256, 0, stream>>>(E, flag, deg);
    int nb = (N_NODES + 1023) / 1024;  // 98
    k_scan1<<<nb, 256, 0, stream>>>(deg, offs, bsum, dinv);
    k_scan2<<<1, 256, 0, stream>>>(bsum, nb);
    k_scan3<<<(N_NODES + 255) / 256, 256, 0, stream>>>(offs, bsum);
    k_fill<<<(N_EDGES + 255) / 256, 256, 0, stream>>>(E, flag, dinv, offs, cursor, csr_src, csr_w);
    k_wsplit<<<32, 256, 0, stream>>>(Wl[1], Wl[2], Wl[3], Wl[4], whi, wlo);

    // layer 0: aggregate (6-wide) then GEMM 6->128 + bias + relu (float4 stores)
    k_agg6<<<(N_NODES + 255) / 256, 256, 0, stream>>>(x, sdf, dinv, offs, csr_src, csr_w, g6);
    k_gemm6<<<(N_NODES + 7) / 8, 256, 0, stream>>>(g6, Wl[0], bl[0], B0);

    // layers 1..4: MFMA GEMM 128->128 (bf16 out) then aggregate + bias + relu (fp32 out)
    const int GGRID = (N_NODES + 63) / 64;
    for (int l = 1; l <= 4; l++) {
        size_t lo = (size_t)(l - 1) * 16384;
        k_gemm128m<<<GGRID, 256, 0, stream>>>(B0, whi + lo, wlo + lo, B1);
        k_agg128<<<(N_NODES + 15) / 16, 256, 0, stream>>>(B1, bl[l], dinv, offs, csr_src, csr_w, B0);
    }

    // layer 5: GEMM 128->3 then aggregate + bias (no relu)
    k_gemm3<<<(N_NODES + 255) / 256, 256, 0, stream>>>(B0, Wl[5], xw3);
    k_agg3<<<(N_NODES + 255) / 256, 256, 0, stream>>>(xw3, bl[5], dinv, offs, csr_src, csr_w, (float*)d_out);
}